// Round 1
// baseline (1117.236 us; speedup 1.0000x reference)
//
#include <hip/hip_runtime.h>

// Problem constants (fixed by reference)
constexpr int NN = 100000;   // nodes
constexpr int EE = 1600000;  // edges
constexpr int NB = 98;       // scan blocks: ceil(100000/1024)

// ---------------- CSR build (sort edges by dst, once per call) ----------------

__global__ __launch_bounds__(256) void k_hist(const int* __restrict__ dst,
                                              int* __restrict__ cnt) {
  int e = blockIdx.x * 256 + threadIdx.x;
  if (e < EE) atomicAdd(&cnt[dst[e]], 1);
}

// per-block (1024 elems) exclusive scan; partial offsets + block sums
__global__ __launch_bounds__(256) void k_scan1(const int* __restrict__ cnt,
                                               int* __restrict__ off,
                                               int* __restrict__ bsum) {
  __shared__ int sh[256];
  const int tid = threadIdx.x;
  const int base = blockIdx.x * 1024 + tid * 4;
  int c0 = (base + 0 < NN) ? cnt[base + 0] : 0;
  int c1 = (base + 1 < NN) ? cnt[base + 1] : 0;
  int c2 = (base + 2 < NN) ? cnt[base + 2] : 0;
  int c3 = (base + 3 < NN) ? cnt[base + 3] : 0;
  const int tsum = c0 + c1 + c2 + c3;
  sh[tid] = tsum;
  __syncthreads();
  int run = tsum;
  for (int d = 1; d < 256; d <<= 1) {
    int v = (tid >= d) ? sh[tid - d] : 0;
    __syncthreads();
    run += v;
    sh[tid] = run;
    __syncthreads();
  }
  const int excl = run - tsum;
  if (base + 0 < NN) off[base + 0] = excl;
  if (base + 1 < NN) off[base + 1] = excl + c0;
  if (base + 2 < NN) off[base + 2] = excl + c0 + c1;
  if (base + 3 < NN) off[base + 3] = excl + c0 + c1 + c2;
  if (tid == 255) bsum[blockIdx.x] = run;
}

__global__ void k_scan2(int* __restrict__ bsum) {
  if (threadIdx.x == 0 && blockIdx.x == 0) {
    int run = 0;
    for (int i = 0; i < NB; ++i) { int t = bsum[i]; bsum[i] = run; run += t; }
  }
}

__global__ __launch_bounds__(256) void k_scan3(int* __restrict__ off,
                                               int* __restrict__ cursor,
                                               const int* __restrict__ bsum) {
  int i = blockIdx.x * 256 + threadIdx.x;
  if (i < NN) {
    int v = off[i] + bsum[i >> 10];
    off[i] = v;
    cursor[i] = v;
  }
  if (i == 0) off[NN] = EE;
}

__global__ __launch_bounds__(256) void k_scatter(const int* __restrict__ dst,
                                                 const int* __restrict__ src,
                                                 const int* __restrict__ etype,
                                                 const float* __restrict__ norm,
                                                 int* __restrict__ cursor,
                                                 int* __restrict__ ee,
                                                 float* __restrict__ wsrt) {
  int e = blockIdx.x * 256 + threadIdx.x;
  if (e < EE) {
    int pos = atomicAdd(&cursor[dst[e]], 1);
    ee[pos] = (etype[e] << 20) | src[e];  // src < 2^17, etype < 8
    wsrt[pos] = norm[e];
  }
}

// ---------------- per-layer kernels ----------------

// One wave (64 lanes) per dst node; lane = feature i. Accumulate 4 basis
// planes in registers over the node's sorted edge segment. No atomics.
// AGG layout: [n][b*64 + i]  (row of 256 floats per node, b-major)
__global__ __launch_bounds__(256) void k_agg(const float* __restrict__ h,
                                             const int* __restrict__ off,
                                             const int* __restrict__ ee,
                                             const float* __restrict__ wsrt,
                                             const float* __restrict__ wcomp,
                                             float* __restrict__ AGG) {
  const int lane = threadIdx.x & 63;
  const int n = (blockIdx.x * 256 + threadIdx.x) >> 6;
  const int p0 = off[n];
  const int p1 = off[n + 1];
  float a0 = 0.f, a1 = 0.f, a2 = 0.f, a3 = 0.f;
  for (int p = p0; p < p1; ++p) {
    const int key = ee[p];
    const float wn = wsrt[p];
    const int s = key & 1048575;
    const int et = key >> 20;
    const float hv = h[(size_t)s * 64 + lane];
    const float c0 = wn * wcomp[et * 4 + 0];
    const float c1 = wn * wcomp[et * 4 + 1];
    const float c2 = wn * wcomp[et * 4 + 2];
    const float c3 = wn * wcomp[et * 4 + 3];
    a0 += c0 * hv; a1 += c1 * hv; a2 += c2 * hv; a3 += c3 * hv;
  }
  const size_t base = (size_t)n * 256 + lane;
  AGG[base + 0]   = a0;
  AGG[base + 64]  = a1;
  AGG[base + 128] = a2;
  AGG[base + 192] = a3;
}

// out[n][o] = act( sum_{k=0..255} AGG[n][k] * BB[k][o] ), BB = bases flat (256x64)
// tile = 16 nodes; thread (nl, og) computes node nl, outputs og*4..og*4+3.
__global__ __launch_bounds__(256) void k_gemm(const float* __restrict__ AGG,
                                              const float* __restrict__ BB,
                                              float* __restrict__ out,
                                              int activate) {
  __shared__ float ags[16 * 260];  // +4 pad per row: bank-spread for 4 nl/wave
  __shared__ float bbs[64 * 64];   // one 64-k chunk of BB
  const int tid = threadIdx.x;
  const int og = tid & 15;
  const int nl = tid >> 4;
  for (int tile = blockIdx.x; tile < NN / 16; tile += gridDim.x) {
    const int n0 = tile * 16;
    __syncthreads();  // prev tile fully consumed before ags overwrite
    for (int t = tid; t < 1024; t += 256) {
      const int f = t * 4, row = f >> 8, col = f & 255;
      *(float4*)&ags[row * 260 + col] = *(const float4*)&AGG[(size_t)n0 * 256 + f];
    }
    float4 acc = {0.f, 0.f, 0.f, 0.f};
    for (int kc = 0; kc < 4; ++kc) {
      __syncthreads();  // prev chunk consumed (and ags ready for kc==0)
      for (int t = tid; t < 1024; t += 256)
        *(float4*)&bbs[t * 4] = *(const float4*)&BB[kc * 4096 + t * 4];
      __syncthreads();
      const float* ar = &ags[nl * 260 + kc * 64];
#pragma unroll 8
      for (int k = 0; k < 64; ++k) {
        const float av = ar[k];
        const float4 bv = *(const float4*)&bbs[k * 64 + og * 4];
        acc.x += av * bv.x; acc.y += av * bv.y;
        acc.z += av * bv.z; acc.w += av * bv.w;
      }
    }
    if (activate) {
      acc.x = fmaxf(acc.x, 0.f); acc.y = fmaxf(acc.y, 0.f);
      acc.z = fmaxf(acc.z, 0.f); acc.w = fmaxf(acc.w, 0.f);
    }
    *(float4*)&out[(size_t)(n0 + nl) * 64 + og * 4] = acc;
  }
}

// decoder: rec[n] = b2 + sum_o relu(b1[o] + henc[n,:]@w1[:,o]) * w2[o]
__global__ __launch_bounds__(256) void k_dec(const float* __restrict__ henc,
                                             const float* __restrict__ w1,
                                             const float* __restrict__ b1,
                                             const float* __restrict__ w2,
                                             const float* __restrict__ b2,
                                             float* __restrict__ rec) {
  __shared__ float w1s[64 * 64];
  const int tid = threadIdx.x;
  for (int t = tid; t < 1024; t += 256)
    *(float4*)&w1s[t * 4] = *(const float4*)&w1[t * 4];
  __syncthreads();
  const int lane = tid & 63;
  const int n = (blockIdx.x * 256 + tid) >> 6;
  const float* hr = henc + (size_t)n * 64;
  float acc = b1[lane];
#pragma unroll 8
  for (int i = 0; i < 64; ++i) acc += hr[i] * w1s[i * 64 + lane];
  acc = fmaxf(acc, 0.f);
  float v = acc * w2[lane];
  for (int d = 32; d > 0; d >>= 1) v += __shfl_down(v, d);
  if (lane == 0) rec[n] = v + b2[0];
}

// ---------------- launch ----------------

extern "C" void kernel_launch(void* const* d_in, const int* in_sizes, int n_in,
                              void* d_out, int out_size, void* d_ws, size_t ws_size,
                              hipStream_t stream) {
  const float* h     = (const float*)d_in[0];
  const int*   src   = (const int*)d_in[1];
  const int*   dst   = (const int*)d_in[2];
  const int*   etype = (const int*)d_in[3];
  const float* norm  = (const float*)d_in[4];
  const float* bases[3] = {(const float*)d_in[5], (const float*)d_in[7], (const float*)d_in[9]};
  const float* wcomp[3] = {(const float*)d_in[6], (const float*)d_in[8], (const float*)d_in[10]};
  const float* dw1 = (const float*)d_in[11];
  const float* db1 = (const float*)d_in[12];
  const float* dw2 = (const float*)d_in[13];
  const float* db2 = (const float*)d_in[14];

  float* rec  = (float*)d_out;        // [N]
  float* henc = (float*)d_out + NN;   // [N,64]

  // workspace carve-up (aligned)
  char* ws = (char*)d_ws;
  int*   off    = (int*)(ws + 0);                 // (N+1) ints
  int*   cursor = (int*)(ws + 400128);            // N ints (counts, then cursor)
  int*   bsum   = (int*)(ws + 800256);            // NB ints
  int*   ee     = (int*)(ws + 800768);            // E ints (etype<<20 | src, sorted)
  float* wsrt   = (float*)(ws + 800768 + 6400000);   // E floats (norm, sorted)
  float* AGG    = (float*)(ws + 800768 + 12800000);  // N*256 floats
  float* h1     = AGG + (size_t)NN * 256;            // N*64
  float* h2     = h1 + (size_t)NN * 64;              // N*64

  // ---- build dst-sorted CSR (reused by all 3 layers) ----
  hipMemsetAsync(cursor, 0, NN * sizeof(int), stream);
  k_hist<<<EE / 256, 256, 0, stream>>>(dst, cursor);
  k_scan1<<<NB, 256, 0, stream>>>(cursor, off, bsum);
  k_scan2<<<1, 64, 0, stream>>>(bsum);
  k_scan3<<<(NN + 255) / 256, 256, 0, stream>>>(off, cursor, bsum);
  k_scatter<<<EE / 256, 256, 0, stream>>>(dst, src, etype, norm, cursor, ee, wsrt);

  // ---- layer 1: h -> h1 (relu) ----
  k_agg<<<NN / 4, 256, 0, stream>>>(h, off, ee, wsrt, wcomp[0], AGG);
  k_gemm<<<1024, 256, 0, stream>>>(AGG, bases[0], h1, 1);
  // ---- layer 2: h1 -> h2 (relu) ----
  k_agg<<<NN / 4, 256, 0, stream>>>(h1, off, ee, wsrt, wcomp[1], AGG);
  k_gemm<<<1024, 256, 0, stream>>>(AGG, bases[1], h2, 1);
  // ---- layer 3: h2 -> henc (no act) ----
  k_agg<<<NN / 4, 256, 0, stream>>>(h2, off, ee, wsrt, wcomp[2], AGG);
  k_gemm<<<1024, 256, 0, stream>>>(AGG, bases[2], henc, 0);
  // ---- decoder ----
  k_dec<<<NN / 4, 256, 0, stream>>>(henc, dw1, db1, dw2, db2, rec);
}

// Round 2
// 815.100 us; speedup vs baseline: 1.3707x; 1.3707x over previous
//
#include <hip/hip_runtime.h>

// Problem constants (fixed by reference)
constexpr int NN = 100000;   // nodes
constexpr int EE = 1600000;  // edges
constexpr int NB = 98;       // scan blocks: ceil(100000/1024)

// ---------------- CSR build (sort edges by dst, once per call) ----------------

__global__ __launch_bounds__(256) void k_hist(const int* __restrict__ dst,
                                              int* __restrict__ cnt) {
  int e = blockIdx.x * 256 + threadIdx.x;
  if (e < EE) atomicAdd(&cnt[dst[e]], 1);
}

__global__ __launch_bounds__(256) void k_scan1(const int* __restrict__ cnt,
                                               int* __restrict__ off,
                                               int* __restrict__ bsum) {
  __shared__ int sh[256];
  const int tid = threadIdx.x;
  const int base = blockIdx.x * 1024 + tid * 4;
  int c0 = (base + 0 < NN) ? cnt[base + 0] : 0;
  int c1 = (base + 1 < NN) ? cnt[base + 1] : 0;
  int c2 = (base + 2 < NN) ? cnt[base + 2] : 0;
  int c3 = (base + 3 < NN) ? cnt[base + 3] : 0;
  const int tsum = c0 + c1 + c2 + c3;
  sh[tid] = tsum;
  __syncthreads();
  int run = tsum;
  for (int d = 1; d < 256; d <<= 1) {
    int v = (tid >= d) ? sh[tid - d] : 0;
    __syncthreads();
    run += v;
    sh[tid] = run;
    __syncthreads();
  }
  const int excl = run - tsum;
  if (base + 0 < NN) off[base + 0] = excl;
  if (base + 1 < NN) off[base + 1] = excl + c0;
  if (base + 2 < NN) off[base + 2] = excl + c0 + c1;
  if (base + 3 < NN) off[base + 3] = excl + c0 + c1 + c2;
  if (tid == 255) bsum[blockIdx.x] = run;
}

__global__ void k_scan2(int* __restrict__ bsum) {
  if (threadIdx.x == 0 && blockIdx.x == 0) {
    int run = 0;
    for (int i = 0; i < NB; ++i) { int t = bsum[i]; bsum[i] = run; run += t; }
  }
}

__global__ __launch_bounds__(256) void k_scan3(int* __restrict__ off,
                                               int* __restrict__ cursor,
                                               const int* __restrict__ bsum) {
  int i = blockIdx.x * 256 + threadIdx.x;
  if (i < NN) {
    int v = off[i] + bsum[i >> 10];
    off[i] = v;
    cursor[i] = v;
  }
  if (i == 0) off[NN] = EE;
}

__global__ __launch_bounds__(256) void k_scatter(const int* __restrict__ dst,
                                                 const int* __restrict__ src,
                                                 const int* __restrict__ etype,
                                                 const float* __restrict__ norm,
                                                 int* __restrict__ cursor,
                                                 int2* __restrict__ em) {
  int e = blockIdx.x * 256 + threadIdx.x;
  if (e < EE) {
    int pos = atomicAdd(&cursor[dst[e]], 1);
    em[pos] = make_int2((etype[e] << 20) | src[e], __float_as_int(norm[e]));
  }
}

// ---------------- per-layer kernels ----------------

// One wave per dst node; lane = feature. 4 basis accumulators in registers.
// Unroll-by-4 over the edge segment for memory-level parallelism.
__global__ __launch_bounds__(256) void k_agg(const float* __restrict__ h,
                                             const int* __restrict__ off,
                                             const int2* __restrict__ em,
                                             const float* __restrict__ wcomp,  // [8][4]
                                             float* __restrict__ AGG) {
  const int lane = threadIdx.x & 63;
  const int n = (blockIdx.x * 256 + threadIdx.x) >> 6;
  const float4* __restrict__ wc4 = (const float4*)wcomp;
  const int p0 = off[n], p1 = off[n + 1];
  float a0 = 0.f, a1 = 0.f, a2 = 0.f, a3 = 0.f;
  int p = p0;
  for (; p + 4 <= p1; p += 4) {
    const int2 m0 = em[p + 0], m1 = em[p + 1], m2 = em[p + 2], m3 = em[p + 3];
    const float hv0 = h[(size_t)(m0.x & 0xFFFFF) * 64 + lane];
    const float hv1 = h[(size_t)(m1.x & 0xFFFFF) * 64 + lane];
    const float hv2 = h[(size_t)(m2.x & 0xFFFFF) * 64 + lane];
    const float hv3 = h[(size_t)(m3.x & 0xFFFFF) * 64 + lane];
    const float4 w0 = wc4[m0.x >> 20], w1 = wc4[m1.x >> 20];
    const float4 w2 = wc4[m2.x >> 20], w3 = wc4[m3.x >> 20];
    const float t0 = __int_as_float(m0.y) * hv0;
    const float t1 = __int_as_float(m1.y) * hv1;
    const float t2 = __int_as_float(m2.y) * hv2;
    const float t3 = __int_as_float(m3.y) * hv3;
    a0 += t0 * w0.x; a1 += t0 * w0.y; a2 += t0 * w0.z; a3 += t0 * w0.w;
    a0 += t1 * w1.x; a1 += t1 * w1.y; a2 += t1 * w1.z; a3 += t1 * w1.w;
    a0 += t2 * w2.x; a1 += t2 * w2.y; a2 += t2 * w2.z; a3 += t2 * w2.w;
    a0 += t3 * w3.x; a1 += t3 * w3.y; a2 += t3 * w3.z; a3 += t3 * w3.w;
  }
  for (; p < p1; ++p) {
    const int2 m = em[p];
    const float hv = h[(size_t)(m.x & 0xFFFFF) * 64 + lane];
    const float4 w = wc4[m.x >> 20];
    const float t = __int_as_float(m.y) * hv;
    a0 += t * w.x; a1 += t * w.y; a2 += t * w.z; a3 += t * w.w;
  }
  const size_t base = (size_t)n * 256 + lane;
  AGG[base + 0]   = a0;
  AGG[base + 64]  = a1;
  AGG[base + 128] = a2;
  AGG[base + 192] = a3;
}

// out[n][o] = act( sum_{k<256} AGG[n][k] * BB[k][o] )
// BB (64 KB) persistent in LDS; AGG staged transposed [k][n] in 32-k chunks,
// double-buffered. Thread tile: 8 nodes x 8 outs (64 FMA per 4 ds_read_b128).
__global__ __launch_bounds__(256) void k_gemm(const float* __restrict__ AGG,
                                              const float* __restrict__ BB,
                                              float* __restrict__ out,
                                              int activate) {
  __shared__ float bbs[256 * 64];     // 64 KB, persistent
  __shared__ float ats[2][32 * 256];  // 2 x 32 KB, [k][n] transposed
  const int tid = threadIdx.x;
  const int og = tid & 7;    // outs og*8..+7
  const int ng = tid >> 3;   // nodes ng*8..+7
  const int n0 = blockIdx.x * 256;
  const int nrem = NN - n0;  // 160 for the last block

  for (int r = tid; r < 4096; r += 256)
    *(float4*)&bbs[r * 4] = *(const float4*)&BB[r * 4];

  // stage chunk 0 (thread tid owns node tid's 32-float k-chunk)
  {
    float4 v[8];
    if (tid < nrem) {
      const float* ap = &AGG[(size_t)(n0 + tid) * 256];
#pragma unroll
      for (int r = 0; r < 8; ++r) v[r] = *(const float4*)&ap[r * 4];
    } else {
#pragma unroll
      for (int r = 0; r < 8; ++r) v[r] = make_float4(0.f, 0.f, 0.f, 0.f);
    }
#pragma unroll
    for (int r = 0; r < 8; ++r) {
      ats[0][(r * 4 + 0) * 256 + tid] = v[r].x;
      ats[0][(r * 4 + 1) * 256 + tid] = v[r].y;
      ats[0][(r * 4 + 2) * 256 + tid] = v[r].z;
      ats[0][(r * 4 + 3) * 256 + tid] = v[r].w;
    }
  }
  __syncthreads();

  float acc[8][8];
#pragma unroll
  for (int i = 0; i < 8; ++i)
#pragma unroll
    for (int j = 0; j < 8; ++j) acc[i][j] = 0.f;

  for (int kc = 0; kc < 8; ++kc) {
    // issue next chunk's global loads (land during compute)
    float4 v[8];
    if (kc < 7) {
      if (tid < nrem) {
        const float* ap = &AGG[(size_t)(n0 + tid) * 256 + (kc + 1) * 32];
#pragma unroll
        for (int r = 0; r < 8; ++r) v[r] = *(const float4*)&ap[r * 4];
      } else {
#pragma unroll
        for (int r = 0; r < 8; ++r) v[r] = make_float4(0.f, 0.f, 0.f, 0.f);
      }
    }
    const float* at = ats[kc & 1];
    const float* bp = &bbs[kc * 32 * 64];
#pragma unroll 8
    for (int k = 0; k < 32; ++k) {
      const float4 A0 = *(const float4*)&at[k * 256 + ng * 8];
      const float4 A1 = *(const float4*)&at[k * 256 + ng * 8 + 4];
      const float4 B0 = *(const float4*)&bp[k * 64 + og * 8];
      const float4 B1 = *(const float4*)&bp[k * 64 + og * 8 + 4];
      const float av[8] = {A0.x, A0.y, A0.z, A0.w, A1.x, A1.y, A1.z, A1.w};
      const float bv[8] = {B0.x, B0.y, B0.z, B0.w, B1.x, B1.y, B1.z, B1.w};
#pragma unroll
      for (int i = 0; i < 8; ++i)
#pragma unroll
        for (int j = 0; j < 8; ++j) acc[i][j] = fmaf(av[i], bv[j], acc[i][j]);
    }
    if (kc < 7) {
      float* dp = ats[(kc + 1) & 1];
#pragma unroll
      for (int r = 0; r < 8; ++r) {
        dp[(r * 4 + 0) * 256 + tid] = v[r].x;
        dp[(r * 4 + 1) * 256 + tid] = v[r].y;
        dp[(r * 4 + 2) * 256 + tid] = v[r].z;
        dp[(r * 4 + 3) * 256 + tid] = v[r].w;
      }
    }
    __syncthreads();
  }

#pragma unroll
  for (int i = 0; i < 8; ++i) {
    const int nn = n0 + ng * 8 + i;
    if (nn < NN) {
      float4 o0 = make_float4(acc[i][0], acc[i][1], acc[i][2], acc[i][3]);
      float4 o1 = make_float4(acc[i][4], acc[i][5], acc[i][6], acc[i][7]);
      if (activate) {
        o0.x = fmaxf(o0.x, 0.f); o0.y = fmaxf(o0.y, 0.f);
        o0.z = fmaxf(o0.z, 0.f); o0.w = fmaxf(o0.w, 0.f);
        o1.x = fmaxf(o1.x, 0.f); o1.y = fmaxf(o1.y, 0.f);
        o1.z = fmaxf(o1.z, 0.f); o1.w = fmaxf(o1.w, 0.f);
      }
      *(float4*)&out[(size_t)nn * 64 + og * 8] = o0;
      *(float4*)&out[(size_t)nn * 64 + og * 8 + 4] = o1;
    }
  }
}

// decoder: rec[n] = b2 + sum_o relu(b1[o] + henc[n,:]@w1[:,o]) * w2[o]
// thread = (node-local nl, out-group og of 4); float4 weight reads.
__global__ __launch_bounds__(256) void k_dec(const float* __restrict__ henc,
                                             const float* __restrict__ w1,
                                             const float* __restrict__ b1,
                                             const float* __restrict__ w2,
                                             const float* __restrict__ b2,
                                             float* __restrict__ rec) {
  __shared__ float w1s[64 * 64];
  __shared__ float hs[16 * 68];  // stride 68: bank-spread + float4-aligned
  const int tid = threadIdx.x;
  for (int r = tid; r < 1024; r += 256)
    *(float4*)&w1s[r * 4] = *(const float4*)&w1[r * 4];
  const int og = tid & 15;   // outs og*4..+3
  const int nl = tid >> 4;   // 16 nodes per tile
  const float4 wv2 = *(const float4*)&w2[og * 4];
  const float4 bv1 = *(const float4*)&b1[og * 4];
  const float b2v = b2[0];
  for (int t0 = blockIdx.x * 16; t0 < NN; t0 += gridDim.x * 16) {
    __syncthreads();  // previous hs fully consumed
    {
      const float4 hv = *(const float4*)&henc[(size_t)t0 * 64 + tid * 4];
      *(float4*)&hs[(tid >> 4) * 68 + (tid & 15) * 4] = hv;
    }
    __syncthreads();
    float4 acc = bv1;
    const float* hr = &hs[nl * 68];
#pragma unroll 8
    for (int i = 0; i < 64; ++i) {
      const float hv = hr[i];
      const float4 wv = *(const float4*)&w1s[i * 64 + og * 4];
      acc.x = fmaf(hv, wv.x, acc.x); acc.y = fmaf(hv, wv.y, acc.y);
      acc.z = fmaf(hv, wv.z, acc.z); acc.w = fmaf(hv, wv.w, acc.w);
    }
    acc.x = fmaxf(acc.x, 0.f); acc.y = fmaxf(acc.y, 0.f);
    acc.z = fmaxf(acc.z, 0.f); acc.w = fmaxf(acc.w, 0.f);
    float v = acc.x * wv2.x + acc.y * wv2.y + acc.z * wv2.z + acc.w * wv2.w;
    v += __shfl_xor(v, 1); v += __shfl_xor(v, 2);
    v += __shfl_xor(v, 4); v += __shfl_xor(v, 8);
    if (og == 0) rec[t0 + nl] = v + b2v;
  }
}

// ---------------- launch ----------------

extern "C" void kernel_launch(void* const* d_in, const int* in_sizes, int n_in,
                              void* d_out, int out_size, void* d_ws, size_t ws_size,
                              hipStream_t stream) {
  const float* h     = (const float*)d_in[0];
  const int*   src   = (const int*)d_in[1];
  const int*   dst   = (const int*)d_in[2];
  const int*   etype = (const int*)d_in[3];
  const float* norm  = (const float*)d_in[4];
  const float* bases[3] = {(const float*)d_in[5], (const float*)d_in[7], (const float*)d_in[9]};
  const float* wcomp[3] = {(const float*)d_in[6], (const float*)d_in[8], (const float*)d_in[10]};
  const float* dw1 = (const float*)d_in[11];
  const float* db1 = (const float*)d_in[12];
  const float* dw2 = (const float*)d_in[13];
  const float* db2 = (const float*)d_in[14];

  float* rec  = (float*)d_out;        // [N]
  float* henc = (float*)d_out + NN;   // [N,64]

  // workspace carve-up
  char* ws = (char*)d_ws;
  int*   off    = (int*)(ws + 0);            // (N+1) ints
  int*   cursor = (int*)(ws + 400128);       // N ints (counts, then cursor)
  int*   bsum   = (int*)(ws + 800256);       // NB ints
  int2*  em     = (int2*)(ws + 800768);      // E x {key, norm_bits}, dst-sorted
  float* AGG    = (float*)(ws + 800768 + 12800000);  // N*256 floats
  float* h1     = AGG + (size_t)NN * 256;            // N*64
  float* h2     = h1 + (size_t)NN * 64;              // N*64

  // ---- build dst-sorted CSR (reused by all 3 layers) ----
  hipMemsetAsync(cursor, 0, NN * sizeof(int), stream);
  k_hist<<<EE / 256, 256, 0, stream>>>(dst, cursor);
  k_scan1<<<NB, 256, 0, stream>>>(cursor, off, bsum);
  k_scan2<<<1, 64, 0, stream>>>(bsum);
  k_scan3<<<(NN + 255) / 256, 256, 0, stream>>>(off, cursor, bsum);
  k_scatter<<<EE / 256, 256, 0, stream>>>(dst, src, etype, norm, cursor, em);

  const int gemm_grid = (NN + 255) / 256;  // 391
  // ---- layer 1 ----
  k_agg<<<NN / 4, 256, 0, stream>>>(h, off, em, wcomp[0], AGG);
  k_gemm<<<gemm_grid, 256, 0, stream>>>(AGG, bases[0], h1, 1);
  // ---- layer 2 ----
  k_agg<<<NN / 4, 256, 0, stream>>>(h1, off, em, wcomp[1], AGG);
  k_gemm<<<gemm_grid, 256, 0, stream>>>(AGG, bases[1], h2, 1);
  // ---- layer 3 ----
  k_agg<<<NN / 4, 256, 0, stream>>>(h2, off, em, wcomp[2], AGG);
  k_gemm<<<gemm_grid, 256, 0, stream>>>(AGG, bases[2], henc, 0);
  // ---- decoder ----
  k_dec<<<256, 256, 0, stream>>>(henc, dw1, db1, dw2, db2, rec);
}

// Round 3
// 697.686 us; speedup vs baseline: 1.6013x; 1.1683x over previous
//
#include <hip/hip_runtime.h>

typedef _Float16 half8 __attribute__((ext_vector_type(8)));
typedef _Float16 half4 __attribute__((ext_vector_type(4)));
typedef float floatx4 __attribute__((ext_vector_type(4)));

// Problem constants (fixed by reference)
constexpr int NN = 100000;   // nodes
constexpr int EE = 1600000;  // edges
constexpr int NB = 98;       // scan blocks: ceil(100000/1024)

// ---------------- CSR build (sort edges by dst, once per call) ----------------

__global__ __launch_bounds__(256) void k_hist(const int* __restrict__ dst,
                                              int* __restrict__ cnt) {
  int e = blockIdx.x * 256 + threadIdx.x;
  if (e < EE) atomicAdd(&cnt[dst[e]], 1);
}

__global__ __launch_bounds__(256) void k_scan1(const int* __restrict__ cnt,
                                               int* __restrict__ off,
                                               int* __restrict__ bsum) {
  __shared__ int sh[256];
  const int tid = threadIdx.x;
  const int base = blockIdx.x * 1024 + tid * 4;
  int c0 = (base + 0 < NN) ? cnt[base + 0] : 0;
  int c1 = (base + 1 < NN) ? cnt[base + 1] : 0;
  int c2 = (base + 2 < NN) ? cnt[base + 2] : 0;
  int c3 = (base + 3 < NN) ? cnt[base + 3] : 0;
  const int tsum = c0 + c1 + c2 + c3;
  sh[tid] = tsum;
  __syncthreads();
  int run = tsum;
  for (int d = 1; d < 256; d <<= 1) {
    int v = (tid >= d) ? sh[tid - d] : 0;
    __syncthreads();
    run += v;
    sh[tid] = run;
    __syncthreads();
  }
  const int excl = run - tsum;
  if (base + 0 < NN) off[base + 0] = excl;
  if (base + 1 < NN) off[base + 1] = excl + c0;
  if (base + 2 < NN) off[base + 2] = excl + c0 + c1;
  if (base + 3 < NN) off[base + 3] = excl + c0 + c1 + c2;
  if (tid == 255) bsum[blockIdx.x] = run;
}

__global__ void k_scan2(int* __restrict__ bsum) {
  if (threadIdx.x == 0 && blockIdx.x == 0) {
    int run = 0;
    for (int i = 0; i < NB; ++i) { int t = bsum[i]; bsum[i] = run; run += t; }
  }
}

__global__ __launch_bounds__(256) void k_scan3(int* __restrict__ off,
                                               int* __restrict__ cursor,
                                               const int* __restrict__ bsum) {
  int i = blockIdx.x * 256 + threadIdx.x;
  if (i < NN) {
    int v = off[i] + bsum[i >> 10];
    off[i] = v;
    cursor[i] = v;
  }
  if (i == 0) off[NN] = EE;
}

__global__ __launch_bounds__(256) void k_scatter(const int* __restrict__ dst,
                                                 const int* __restrict__ src,
                                                 const int* __restrict__ etype,
                                                 const float* __restrict__ norm,
                                                 int* __restrict__ cursor,
                                                 int2* __restrict__ em) {
  int e = blockIdx.x * 256 + threadIdx.x;
  if (e < EE) {
    int pos = atomicAdd(&cursor[dst[e]], 1);
    em[pos] = make_int2((etype[e] << 20) | src[e], __float_as_int(norm[e]));
  }
}

// ---------------- prep: fp16 conversions ----------------

__global__ __launch_bounds__(256) void k_prep_h(const float* __restrict__ h,
                                                _Float16* __restrict__ hh) {
  const int i = blockIdx.x * 256 + threadIdx.x;  // quads, 1.6M total
  const float4 v = *(const float4*)&h[(size_t)i * 4];
  half4 o = {(_Float16)v.x, (_Float16)v.y, (_Float16)v.z, (_Float16)v.w};
  *(half4*)&hh[(size_t)i * 4] = o;
}

// bbt[o][k] = bases[b][i][o] with k = b*64 + i, fp16 (one launch per layer)
__global__ __launch_bounds__(256) void k_prep_b(const float* __restrict__ bases,
                                                _Float16* __restrict__ bbt) {
  const int idx = blockIdx.x * 256 + threadIdx.x;  // 16384
  const int o = idx >> 8, k = idx & 255;
  const int b = k >> 6, i = k & 63;
  bbt[idx] = (_Float16)bases[b * 4096 + i * 64 + o];
}

// ---------------- fused layer: gather + basis-GEMM (MFMA) ----------------
// Block = 16 dst nodes. Each wave aggregates 4 nodes (lane = feature) into
// 4 fp32 basis accumulators, spills AGG[16][256] as fp16 to LDS, then each
// wave computes a 16-node x 16-out MFMA chain (K=256) with B-frags in regs.
__global__ __launch_bounds__(256) void k_layer(const _Float16* __restrict__ hh,
                                               const int* __restrict__ off,
                                               const int2* __restrict__ em,
                                               const float* __restrict__ wcomp,  // [8][4]
                                               const _Float16* __restrict__ bbt, // [64][256]
                                               _Float16* __restrict__ out16,     // relu, layers 1/2
                                               float* __restrict__ out32) {      // no act, layer 3
  __shared__ _Float16 Ash[16 * 264];  // rows stride 264 f16 = 528 B (16B-aligned)
  const int tid = threadIdx.x;
  const int lane = tid & 63;
  const int wv = tid >> 6;
  const int n0 = blockIdx.x * 16;
  const float4* __restrict__ wc4 = (const float4*)wcomp;

  for (int q = 0; q < 4; ++q) {
    const int m = wv * 4 + q;
    const int n = n0 + m;
    const int p0 = off[n], p1 = off[n + 1];
    float a0 = 0.f, a1 = 0.f, a2 = 0.f, a3 = 0.f;
    int p = p0;
    for (; p + 4 <= p1; p += 4) {
      const int2 m0 = em[p + 0], m1 = em[p + 1], m2 = em[p + 2], m3 = em[p + 3];
      const float hv0 = (float)hh[(size_t)(m0.x & 0xFFFFF) * 64 + lane];
      const float hv1 = (float)hh[(size_t)(m1.x & 0xFFFFF) * 64 + lane];
      const float hv2 = (float)hh[(size_t)(m2.x & 0xFFFFF) * 64 + lane];
      const float hv3 = (float)hh[(size_t)(m3.x & 0xFFFFF) * 64 + lane];
      const float4 w0 = wc4[m0.x >> 20], w1 = wc4[m1.x >> 20];
      const float4 w2 = wc4[m2.x >> 20], w3 = wc4[m3.x >> 20];
      const float t0 = __int_as_float(m0.y) * hv0;
      const float t1 = __int_as_float(m1.y) * hv1;
      const float t2 = __int_as_float(m2.y) * hv2;
      const float t3 = __int_as_float(m3.y) * hv3;
      a0 += t0 * w0.x; a1 += t0 * w0.y; a2 += t0 * w0.z; a3 += t0 * w0.w;
      a0 += t1 * w1.x; a1 += t1 * w1.y; a2 += t1 * w1.z; a3 += t1 * w1.w;
      a0 += t2 * w2.x; a1 += t2 * w2.y; a2 += t2 * w2.z; a3 += t2 * w2.w;
      a0 += t3 * w3.x; a1 += t3 * w3.y; a2 += t3 * w3.z; a3 += t3 * w3.w;
    }
    for (; p < p1; ++p) {
      const int2 mm = em[p];
      const float hv = (float)hh[(size_t)(mm.x & 0xFFFFF) * 64 + lane];
      const float4 w = wc4[mm.x >> 20];
      const float t = __int_as_float(mm.y) * hv;
      a0 += t * w.x; a1 += t * w.y; a2 += t * w.z; a3 += t * w.w;
    }
    _Float16* ar = &Ash[m * 264];
    ar[lane]       = (_Float16)a0;
    ar[64 + lane]  = (_Float16)a1;
    ar[128 + lane] = (_Float16)a2;
    ar[192 + lane] = (_Float16)a3;
  }
  __syncthreads();

  // MFMA: C[16 nodes][16 outs] per wave, outs = wv*16 .. +15, K = 256.
  // A-frag: A[m = lane&15][k = (lane>>4)*8 + j]; B-frag: B[k][n = lane&15].
  const int col = lane & 15;
  const int quad = lane >> 4;
  const int obase = wv * 16 + col;
  const _Float16* ap = &Ash[col * 264 + quad * 8];
  const _Float16* bp = &bbt[(size_t)obase * 256 + quad * 8];
  floatx4 acc = {0.f, 0.f, 0.f, 0.f};
#pragma unroll
  for (int s = 0; s < 8; ++s) {
    const half8 af = *(const half8*)(ap + s * 32);
    const half8 bf = *(const half8*)(bp + s * 32);
    acc = __builtin_amdgcn_mfma_f32_16x16x32_f16(af, bf, acc, 0, 0, 0);
  }
  // C/D: row(node) = quad*4 + r, col(out) = obase
  if (out16) {
#pragma unroll
    for (int r = 0; r < 4; ++r) {
      const float c = fmaxf(acc[r], 0.f);
      out16[(size_t)(n0 + quad * 4 + r) * 64 + obase] = (_Float16)c;
    }
  } else {
#pragma unroll
    for (int r = 0; r < 4; ++r) {
      out32[(size_t)(n0 + quad * 4 + r) * 64 + obase] = acc[r];
    }
  }
}

// decoder: rec[n] = b2 + sum_o relu(b1[o] + henc[n,:]@w1[:,o]) * w2[o]
__global__ __launch_bounds__(256) void k_dec(const float* __restrict__ henc,
                                             const float* __restrict__ w1,
                                             const float* __restrict__ b1,
                                             const float* __restrict__ w2,
                                             const float* __restrict__ b2,
                                             float* __restrict__ rec) {
  __shared__ float w1s[64 * 64];
  __shared__ float hs[16 * 68];
  const int tid = threadIdx.x;
  for (int r = tid; r < 1024; r += 256)
    *(float4*)&w1s[r * 4] = *(const float4*)&w1[r * 4];
  const int og = tid & 15;
  const int nl = tid >> 4;
  const float4 wv2 = *(const float4*)&w2[og * 4];
  const float4 bv1 = *(const float4*)&b1[og * 4];
  const float b2v = b2[0];
  for (int t0 = blockIdx.x * 16; t0 < NN; t0 += gridDim.x * 16) {
    __syncthreads();
    {
      const float4 hv = *(const float4*)&henc[(size_t)t0 * 64 + tid * 4];
      *(float4*)&hs[(tid >> 4) * 68 + (tid & 15) * 4] = hv;
    }
    __syncthreads();
    float4 acc = bv1;
    const float* hr = &hs[nl * 68];
#pragma unroll 8
    for (int i = 0; i < 64; ++i) {
      const float hv = hr[i];
      const float4 wv = *(const float4*)&w1s[i * 64 + og * 4];
      acc.x = fmaf(hv, wv.x, acc.x); acc.y = fmaf(hv, wv.y, acc.y);
      acc.z = fmaf(hv, wv.z, acc.z); acc.w = fmaf(hv, wv.w, acc.w);
    }
    acc.x = fmaxf(acc.x, 0.f); acc.y = fmaxf(acc.y, 0.f);
    acc.z = fmaxf(acc.z, 0.f); acc.w = fmaxf(acc.w, 0.f);
    float v = acc.x * wv2.x + acc.y * wv2.y + acc.z * wv2.z + acc.w * wv2.w;
    v += __shfl_xor(v, 1); v += __shfl_xor(v, 2);
    v += __shfl_xor(v, 4); v += __shfl_xor(v, 8);
    if (og == 0) rec[t0 + nl] = v + b2v;
  }
}

// ---------------- launch ----------------

extern "C" void kernel_launch(void* const* d_in, const int* in_sizes, int n_in,
                              void* d_out, int out_size, void* d_ws, size_t ws_size,
                              hipStream_t stream) {
  const float* h     = (const float*)d_in[0];
  const int*   src   = (const int*)d_in[1];
  const int*   dst   = (const int*)d_in[2];
  const int*   etype = (const int*)d_in[3];
  const float* norm  = (const float*)d_in[4];
  const float* bases[3] = {(const float*)d_in[5], (const float*)d_in[7], (const float*)d_in[9]};
  const float* wcomp[3] = {(const float*)d_in[6], (const float*)d_in[8], (const float*)d_in[10]};
  const float* dw1 = (const float*)d_in[11];
  const float* db1 = (const float*)d_in[12];
  const float* dw2 = (const float*)d_in[13];
  const float* db2 = (const float*)d_in[14];

  float* rec  = (float*)d_out;        // [N]
  float* henc = (float*)d_out + NN;   // [N,64] fp32 (also layer-3 output)

  // workspace carve-up (all offsets 16B-aligned)
  char* ws = (char*)d_ws;
  int*      off    = (int*)(ws + 0);           // (N+1) ints
  int*      cursor = (int*)(ws + 400512);      // N ints
  int*      bsum   = (int*)(ws + 800512);      // NB ints
  int2*     em     = (int2*)(ws + 801024);     // E x {key, norm}, dst-sorted
  _Float16* hh     = (_Float16*)(ws + 13601024);  // [N][64] fp16
  _Float16* h1f    = (_Float16*)(ws + 26401024);  // [N][64] fp16
  _Float16* h2f    = (_Float16*)(ws + 39201024);  // [N][64] fp16
  _Float16* bbt0   = (_Float16*)(ws + 52001024);  // [64][256] fp16
  _Float16* bbt1   = bbt0 + 16384;
  _Float16* bbt2   = bbt1 + 16384;

  // ---- build dst-sorted CSR ----
  hipMemsetAsync(cursor, 0, NN * sizeof(int), stream);
  k_hist<<<EE / 256, 256, 0, stream>>>(dst, cursor);
  k_scan1<<<NB, 256, 0, stream>>>(cursor, off, bsum);
  k_scan2<<<1, 64, 0, stream>>>(bsum);
  k_scan3<<<(NN + 255) / 256, 256, 0, stream>>>(off, cursor, bsum);
  k_scatter<<<EE / 256, 256, 0, stream>>>(dst, src, etype, norm, cursor, em);

  // ---- fp16 prep ----
  k_prep_h<<<6250, 256, 0, stream>>>(h, hh);
  k_prep_b<<<64, 256, 0, stream>>>(bases[0], bbt0);
  k_prep_b<<<64, 256, 0, stream>>>(bases[1], bbt1);
  k_prep_b<<<64, 256, 0, stream>>>(bases[2], bbt2);

  // ---- fused layers ----
  k_layer<<<NN / 16, 256, 0, stream>>>(hh,  off, em, wcomp[0], bbt0, h1f, nullptr);
  k_layer<<<NN / 16, 256, 0, stream>>>(h1f, off, em, wcomp[1], bbt1, h2f, nullptr);
  k_layer<<<NN / 16, 256, 0, stream>>>(h2f, off, em, wcomp[2], bbt2, nullptr, henc);

  // ---- decoder ----
  k_dec<<<256, 256, 0, stream>>>(henc, dw1, db1, dw2, db2, rec);
}

// Round 4
// 660.594 us; speedup vs baseline: 1.6913x; 1.0561x over previous
//
#include <hip/hip_runtime.h>

typedef _Float16 half8 __attribute__((ext_vector_type(8)));
typedef _Float16 half4 __attribute__((ext_vector_type(4)));
typedef float floatx4 __attribute__((ext_vector_type(4)));

// Problem constants (fixed by reference)
constexpr int NN = 100000;   // nodes
constexpr int EE = 1600000;  // edges
constexpr int NB = 98;       // scan blocks: ceil(100000/1024)
constexpr int EMCAP = 768;   // LDS edge-staging capacity (mean block load = 256)

// ---------------- CSR build (sort edges by dst, once per call) ----------------

__global__ __launch_bounds__(256) void k_hist(const int4* __restrict__ dst4,
                                              int* __restrict__ cnt) {
  int i = blockIdx.x * 256 + threadIdx.x;  // EE/4 = 400000 int4s
  if (i < EE / 4) {
    const int4 d = dst4[i];
    atomicAdd(&cnt[d.x], 1);
    atomicAdd(&cnt[d.y], 1);
    atomicAdd(&cnt[d.z], 1);
    atomicAdd(&cnt[d.w], 1);
  }
}

__global__ __launch_bounds__(256) void k_scan1(const int* __restrict__ cnt,
                                               int* __restrict__ off,
                                               int* __restrict__ bsum) {
  __shared__ int sh[256];
  const int tid = threadIdx.x;
  const int base = blockIdx.x * 1024 + tid * 4;
  int c0 = (base + 0 < NN) ? cnt[base + 0] : 0;
  int c1 = (base + 1 < NN) ? cnt[base + 1] : 0;
  int c2 = (base + 2 < NN) ? cnt[base + 2] : 0;
  int c3 = (base + 3 < NN) ? cnt[base + 3] : 0;
  const int tsum = c0 + c1 + c2 + c3;
  sh[tid] = tsum;
  __syncthreads();
  int run = tsum;
  for (int d = 1; d < 256; d <<= 1) {
    int v = (tid >= d) ? sh[tid - d] : 0;
    __syncthreads();
    run += v;
    sh[tid] = run;
    __syncthreads();
  }
  const int excl = run - tsum;
  if (base + 0 < NN) off[base + 0] = excl;
  if (base + 1 < NN) off[base + 1] = excl + c0;
  if (base + 2 < NN) off[base + 2] = excl + c0 + c1;
  if (base + 3 < NN) off[base + 3] = excl + c0 + c1 + c2;
  if (tid == 255) bsum[blockIdx.x] = run;
}

// parallel exclusive scan of NB=98 block sums (2 waves + shuffle scan)
__global__ __launch_bounds__(128) void k_scan2(int* __restrict__ bsum) {
  __shared__ int tot0;
  const int tid = threadIdx.x;
  const int v = (tid < NB) ? bsum[tid] : 0;
  int incl = v;
  for (int d = 1; d < 64; d <<= 1) {
    const int t = __shfl_up(incl, d);
    if ((tid & 63) >= d) incl += t;
  }
  if (tid == 63) tot0 = incl;
  __syncthreads();
  if (tid >= 64) incl += tot0;
  if (tid < NB) bsum[tid] = incl - v;  // exclusive
}

__global__ __launch_bounds__(256) void k_scan3(int* __restrict__ off,
                                               int* __restrict__ cursor,
                                               const int* __restrict__ bsum) {
  int i = blockIdx.x * 256 + threadIdx.x;
  if (i < NN) {
    int v = off[i] + bsum[i >> 10];
    off[i] = v;
    cursor[i] = v;
  }
  if (i == 0) off[NN] = EE;
}

__global__ __launch_bounds__(256) void k_scatter(const int* __restrict__ dst,
                                                 const int* __restrict__ src,
                                                 const int* __restrict__ etype,
                                                 const float* __restrict__ norm,
                                                 int* __restrict__ cursor,
                                                 int2* __restrict__ em) {
  int e = blockIdx.x * 256 + threadIdx.x;
  if (e < EE) {
    int pos = atomicAdd(&cursor[dst[e]], 1);
    em[pos] = make_int2((etype[e] << 20) | src[e], __float_as_int(norm[e]));
  }
}

// ---------------- prep: fp16 conversions ----------------

__global__ __launch_bounds__(256) void k_prep_h(const float* __restrict__ h,
                                                _Float16* __restrict__ hh) {
  const int i = blockIdx.x * 256 + threadIdx.x;  // quads, 1.6M total
  const float4 v = *(const float4*)&h[(size_t)i * 4];
  half4 o = {(_Float16)v.x, (_Float16)v.y, (_Float16)v.z, (_Float16)v.w};
  *(half4*)&hh[(size_t)i * 4] = o;
}

// bbt[g][o][k] = bases_g[b][i][o], k = b*64+i; all 3 layers in one launch
__global__ __launch_bounds__(256) void k_prep_b(const float* __restrict__ b0,
                                                const float* __restrict__ b1,
                                                const float* __restrict__ b2,
                                                _Float16* __restrict__ bbt) {
  const int g = blockIdx.x >> 6;
  const int idx = (blockIdx.x & 63) * 256 + threadIdx.x;  // 16384 per layer
  const float* bases = (g == 0) ? b0 : (g == 1) ? b1 : b2;
  const int o = idx >> 8, k = idx & 255;
  const int b = k >> 6, i = k & 63;
  bbt[g * 16384 + idx] = (_Float16)bases[b * 4096 + i * 64 + o];
}

// ---------------- fused layer: gather + basis-GEMM (MFMA) ----------------
// Block = 16 dst nodes. Edge metadata for the whole block staged in LDS
// (kills the em->gather dependent-load chain); per node, clamp-padded
// unroll-8 batches keep 8 h-gathers in flight. AGG spilled to LDS as fp16,
// then one 16x16 MFMA chain (K=256) per wave with B-frags from bbt.
__global__ __launch_bounds__(256, 6) void k_layer(const _Float16* __restrict__ hh,
                                                  const int* __restrict__ off,
                                                  const int2* __restrict__ em,
                                                  const float* __restrict__ wcomp,
                                                  const _Float16* __restrict__ bbt,
                                                  _Float16* __restrict__ out16,
                                                  float* __restrict__ out32) {
  __shared__ _Float16 Ash[16 * 264];
  __shared__ int2 ems[EMCAP];
  __shared__ float4 wcs[8];
  const int tid = threadIdx.x;
  const int lane = tid & 63;
  const int wv = tid >> 6;
  const int n0 = blockIdx.x * 16;

  if (tid < 8) wcs[tid] = ((const float4*)wcomp)[tid];
  const int e0 = off[n0];
  const int len = off[n0 + 16] - e0;
  const int slen = (len < EMCAP) ? len : EMCAP;
  for (int i = tid; i < slen; i += 256) ems[i] = em[e0 + i];
  __syncthreads();

  for (int q = 0; q < 4; ++q) {
    const int m = wv * 4 + q;
    const int p0 = off[n0 + m] - e0;
    const int p1 = off[n0 + m + 1] - e0;
    float a0 = 0.f, a1 = 0.f, a2 = 0.f, a3 = 0.f;
    for (int p = p0; p < p1; p += 8) {
      int key[8];
      float wn[8];
#pragma unroll
      for (int j = 0; j < 8; ++j) {
        const bool live = (p + j < p1);
        const int idx = live ? p + j : p1 - 1;  // clamp: duplicate last edge
        const int2 mm = (idx < slen) ? ems[idx] : em[e0 + idx];
        key[j] = mm.x;
        wn[j] = live ? __int_as_float(mm.y) : 0.f;
      }
      float hv[8];
#pragma unroll
      for (int j = 0; j < 8; ++j)
        hv[j] = (float)hh[(size_t)(key[j] & 0xFFFFF) * 64 + lane];
#pragma unroll
      for (int j = 0; j < 8; ++j) {
        const float4 w = wcs[key[j] >> 20];
        const float t = wn[j] * hv[j];
        a0 = fmaf(t, w.x, a0); a1 = fmaf(t, w.y, a1);
        a2 = fmaf(t, w.z, a2); a3 = fmaf(t, w.w, a3);
      }
    }
    _Float16* ar = &Ash[m * 264];
    ar[lane]       = (_Float16)a0;
    ar[64 + lane]  = (_Float16)a1;
    ar[128 + lane] = (_Float16)a2;
    ar[192 + lane] = (_Float16)a3;
  }
  __syncthreads();

  // MFMA: C[16 nodes][16 outs] per wave, outs = wv*16..+15, K = 256.
  const int col = lane & 15;
  const int quad = lane >> 4;
  const int obase = wv * 16 + col;
  const _Float16* ap = &Ash[col * 264 + quad * 8];
  const _Float16* bp = &bbt[(size_t)obase * 256 + quad * 8];
  floatx4 acc = {0.f, 0.f, 0.f, 0.f};
#pragma unroll
  for (int s = 0; s < 8; ++s) {
    const half8 af = *(const half8*)(ap + s * 32);
    const half8 bf = *(const half8*)(bp + s * 32);
    acc = __builtin_amdgcn_mfma_f32_16x16x32_f16(af, bf, acc, 0, 0, 0);
  }
  if (out16) {
#pragma unroll
    for (int r = 0; r < 4; ++r) {
      const float c = fmaxf(acc[r], 0.f);
      out16[(size_t)(n0 + quad * 4 + r) * 64 + obase] = (_Float16)c;
    }
  } else {
#pragma unroll
    for (int r = 0; r < 4; ++r) {
      out32[(size_t)(n0 + quad * 4 + r) * 64 + obase] = acc[r];
    }
  }
}

// decoder: rec[n] = b2 + sum_o relu(b1[o] + henc[n,:]@w1[:,o]) * w2[o]
__global__ __launch_bounds__(256) void k_dec(const float* __restrict__ henc,
                                             const float* __restrict__ w1,
                                             const float* __restrict__ b1,
                                             const float* __restrict__ w2,
                                             const float* __restrict__ b2,
                                             float* __restrict__ rec) {
  __shared__ float w1s[64 * 64];
  __shared__ float hs[16 * 68];
  const int tid = threadIdx.x;
  for (int r = tid; r < 1024; r += 256)
    *(float4*)&w1s[r * 4] = *(const float4*)&w1[r * 4];
  const int og = tid & 15;
  const int nl = tid >> 4;
  const float4 wv2 = *(const float4*)&w2[og * 4];
  const float4 bv1 = *(const float4*)&b1[og * 4];
  const float b2v = b2[0];
  for (int t0 = blockIdx.x * 16; t0 < NN; t0 += gridDim.x * 16) {
    __syncthreads();
    {
      const float4 hv = *(const float4*)&henc[(size_t)t0 * 64 + tid * 4];
      *(float4*)&hs[(tid >> 4) * 68 + (tid & 15) * 4] = hv;
    }
    __syncthreads();
    float4 acc = bv1;
    const float* hr = &hs[nl * 68];
#pragma unroll 8
    for (int i = 0; i < 64; ++i) {
      const float hv = hr[i];
      const float4 wv = *(const float4*)&w1s[i * 64 + og * 4];
      acc.x = fmaf(hv, wv.x, acc.x); acc.y = fmaf(hv, wv.y, acc.y);
      acc.z = fmaf(hv, wv.z, acc.z); acc.w = fmaf(hv, wv.w, acc.w);
    }
    acc.x = fmaxf(acc.x, 0.f); acc.y = fmaxf(acc.y, 0.f);
    acc.z = fmaxf(acc.z, 0.f); acc.w = fmaxf(acc.w, 0.f);
    float v = acc.x * wv2.x + acc.y * wv2.y + acc.z * wv2.z + acc.w * wv2.w;
    v += __shfl_xor(v, 1); v += __shfl_xor(v, 2);
    v += __shfl_xor(v, 4); v += __shfl_xor(v, 8);
    if (og == 0) rec[t0 + nl] = v + b2v;
  }
}

// ---------------- launch ----------------

extern "C" void kernel_launch(void* const* d_in, const int* in_sizes, int n_in,
                              void* d_out, int out_size, void* d_ws, size_t ws_size,
                              hipStream_t stream) {
  const float* h     = (const float*)d_in[0];
  const int*   src   = (const int*)d_in[1];
  const int*   dst   = (const int*)d_in[2];
  const int*   etype = (const int*)d_in[3];
  const float* norm  = (const float*)d_in[4];
  const float* bases[3] = {(const float*)d_in[5], (const float*)d_in[7], (const float*)d_in[9]};
  const float* wcomp[3] = {(const float*)d_in[6], (const float*)d_in[8], (const float*)d_in[10]};
  const float* dw1 = (const float*)d_in[11];
  const float* db1 = (const float*)d_in[12];
  const float* dw2 = (const float*)d_in[13];
  const float* db2 = (const float*)d_in[14];

  float* rec  = (float*)d_out;        // [N]
  float* henc = (float*)d_out + NN;   // [N,64] fp32 (layer-3 output)

  // workspace carve-up (all offsets 16B-aligned)
  char* ws = (char*)d_ws;
  int*      off    = (int*)(ws + 0);           // (N+1) ints
  int*      cursor = (int*)(ws + 400512);      // N ints
  int*      bsum   = (int*)(ws + 800512);      // NB ints
  int2*     em     = (int2*)(ws + 801024);     // E x {key, norm}, dst-sorted
  _Float16* hh     = (_Float16*)(ws + 13601024);  // [N][64] fp16
  _Float16* h1f    = (_Float16*)(ws + 26401024);  // [N][64] fp16
  _Float16* h2f    = (_Float16*)(ws + 39201024);  // [N][64] fp16
  _Float16* bbt    = (_Float16*)(ws + 52001024);  // [3][64][256] fp16

  // ---- build dst-sorted CSR ----
  hipMemsetAsync(cursor, 0, NN * sizeof(int), stream);
  k_hist<<<(EE / 4 + 255) / 256, 256, 0, stream>>>((const int4*)dst, cursor);
  k_scan1<<<NB, 256, 0, stream>>>(cursor, off, bsum);
  k_scan2<<<1, 128, 0, stream>>>(bsum);
  k_scan3<<<(NN + 255) / 256, 256, 0, stream>>>(off, cursor, bsum);
  k_scatter<<<EE / 256, 256, 0, stream>>>(dst, src, etype, norm, cursor, em);

  // ---- fp16 prep ----
  k_prep_h<<<6250, 256, 0, stream>>>(h, hh);
  k_prep_b<<<192, 256, 0, stream>>>(bases[0], bases[1], bases[2], bbt);

  // ---- fused layers ----
  k_layer<<<NN / 16, 256, 0, stream>>>(hh,  off, em, wcomp[0], bbt,         h1f, nullptr);
  k_layer<<<NN / 16, 256, 0, stream>>>(h1f, off, em, wcomp[1], bbt + 16384, h2f, nullptr);
  k_layer<<<NN / 16, 256, 0, stream>>>(h2f, off, em, wcomp[2], bbt + 32768, nullptr, henc);

  // ---- decoder ----
  k_dec<<<256, 256, 0, stream>>>(henc, dw1, db1, dw2, db2, rec);
}

// Round 5
// 469.987 us; speedup vs baseline: 2.3772x; 1.4056x over previous
//
#include <hip/hip_runtime.h>

typedef _Float16 half8 __attribute__((ext_vector_type(8)));
typedef _Float16 half4 __attribute__((ext_vector_type(4)));
typedef float floatx4 __attribute__((ext_vector_type(4)));

// Problem constants (fixed by reference)
constexpr int NN = 100000;   // nodes
constexpr int EE = 1600000;  // edges
constexpr int NB = 98;       // scan blocks: ceil(100000/1024)
constexpr int NBK = 196;     // partition buckets: ceil(100000/512)
constexpr int CHUNK = 6250;  // edges per k_part block (EE/256)
constexpr int NDCAP = 48;    // per-node LDS edge cap in k_layer (mean deg 16)

// ---------------- CSR build ----------------

__global__ __launch_bounds__(256) void k_hist(const int4* __restrict__ dst4,
                                              int* __restrict__ cnt) {
  int i = blockIdx.x * 256 + threadIdx.x;
  if (i < EE / 4) {
    const int4 d = dst4[i];
    atomicAdd(&cnt[d.x], 1);
    atomicAdd(&cnt[d.y], 1);
    atomicAdd(&cnt[d.z], 1);
    atomicAdd(&cnt[d.w], 1);
  }
}

__global__ __launch_bounds__(256) void k_scan1(const int* __restrict__ cnt,
                                               int* __restrict__ off,
                                               int* __restrict__ bsum) {
  __shared__ int sh[256];
  const int tid = threadIdx.x;
  const int base = blockIdx.x * 1024 + tid * 4;
  int c0 = (base + 0 < NN) ? cnt[base + 0] : 0;
  int c1 = (base + 1 < NN) ? cnt[base + 1] : 0;
  int c2 = (base + 2 < NN) ? cnt[base + 2] : 0;
  int c3 = (base + 3 < NN) ? cnt[base + 3] : 0;
  const int tsum = c0 + c1 + c2 + c3;
  sh[tid] = tsum;
  __syncthreads();
  int run = tsum;
  for (int d = 1; d < 256; d <<= 1) {
    int v = (tid >= d) ? sh[tid - d] : 0;
    __syncthreads();
    run += v;
    sh[tid] = run;
    __syncthreads();
  }
  const int excl = run - tsum;
  if (base + 0 < NN) off[base + 0] = excl;
  if (base + 1 < NN) off[base + 1] = excl + c0;
  if (base + 2 < NN) off[base + 2] = excl + c0 + c1;
  if (base + 3 < NN) off[base + 3] = excl + c0 + c1 + c2;
  if (tid == 255) bsum[blockIdx.x] = run;
}

__global__ __launch_bounds__(128) void k_scan2(int* __restrict__ bsum) {
  __shared__ int tot0;
  const int tid = threadIdx.x;
  const int v = (tid < NB) ? bsum[tid] : 0;
  int incl = v;
  for (int d = 1; d < 64; d <<= 1) {
    const int t = __shfl_up(incl, d);
    if ((tid & 63) >= d) incl += t;
  }
  if (tid == 63) tot0 = incl;
  __syncthreads();
  if (tid >= 64) incl += tot0;
  if (tid < NB) bsum[tid] = incl - v;
}

__global__ __launch_bounds__(256) void k_scan3(int* __restrict__ off,
                                               const int* __restrict__ bsum) {
  int i = blockIdx.x * 256 + threadIdx.x;
  if (i < NN) off[i] = off[i] + bsum[i >> 10];
  if (i == 0) off[NN] = EE;
}

__global__ __launch_bounds__(256) void k_initg(const int* __restrict__ off,
                                               int* __restrict__ gcur) {
  int b = threadIdx.x;
  if (b < NBK) gcur[b] = off[b << 9];
}

// ---- pass A: block-local counting sort into coarse buckets (dst>>9) ----
// record: x = (dst<<15) | (src>>2); y = (src&3) | (et<<2) | (norm_fp16<<5)
__global__ __launch_bounds__(256) void k_part(const int* __restrict__ dst,
                                              const int* __restrict__ src,
                                              const int* __restrict__ etype,
                                              const float* __restrict__ norm,
                                              int* __restrict__ gcur,
                                              int2* __restrict__ part) {
  __shared__ int2 ldata[CHUNK];             // 50000 B
  __shared__ unsigned char lbkt[CHUNK];     // 6250 B
  __shared__ int lhist[NBK], lbase[NBK + 1], lcur[NBK], gbase[NBK];
  __shared__ int sh[256];
  const int tid = threadIdx.x;
  const int e0 = blockIdx.x * CHUNK;

  for (int b = tid; b < NBK; b += 256) lhist[b] = 0;
  __syncthreads();
  for (int i = tid; i < CHUNK; i += 256)
    atomicAdd(&lhist[dst[e0 + i] >> 9], 1);
  __syncthreads();
  // scan lhist -> lbase (exclusive), alloc global bases
  {
    const int v = (tid < NBK) ? lhist[tid] : 0;
    sh[tid] = v;
    __syncthreads();
    int run = v;
    for (int d = 1; d < 256; d <<= 1) {
      int t = (tid >= d) ? sh[tid - d] : 0;
      __syncthreads();
      run += t;
      sh[tid] = run;
      __syncthreads();
    }
    if (tid < NBK) {
      lbase[tid] = run - v;
      lcur[tid] = 0;
      gbase[tid] = atomicAdd(&gcur[tid], v);
    }
    if (tid == 0) lbase[NBK] = CHUNK;
  }
  __syncthreads();
  // LDS scatter into bucket order
  for (int i = tid; i < CHUNK; i += 256) {
    const int e = e0 + i;
    const int d = dst[e], s = src[e], et = etype[e];
    const _Float16 nh = (_Float16)norm[e];
    const unsigned short n16 = __builtin_bit_cast(unsigned short, nh);
    const int bk = d >> 9;
    const int pos = lbase[bk] + atomicAdd(&lcur[bk], 1);
    ldata[pos] = make_int2((d << 15) | (s >> 2), (s & 3) | (et << 2) | ((int)n16 << 5));
    lbkt[pos] = (unsigned char)(bk & 0xFF);
  }
  __syncthreads();
  // coalesced copy out per bucket-run
  for (int i = tid; i < CHUNK; i += 256) {
    int bk = (int)lbkt[i];
    // disambiguate the 8-bit bucket id (bk, bk+256 impossible since NBK<256)
    part[gbase[bk] + (i - lbase[bk])] = ldata[i];
  }
}

// ---- pass B: exact placement within each bucket via LDS node cursors ----
__global__ __launch_bounds__(256) void k_part2(const int* __restrict__ off,
                                               const int2* __restrict__ part,
                                               int2* __restrict__ em) {
  __shared__ int ncur[512];
  const int tid = threadIdx.x;
  const int nb0 = blockIdx.x << 9;
  for (int i = tid; i < 512; i += 256) {
    const int n = nb0 + i;
    ncur[i] = (n < NN) ? off[n] : EE;
  }
  __syncthreads();
  const int g0 = off[nb0];
  const int nend = (nb0 + 512 < NN) ? nb0 + 512 : NN;
  const int g1 = off[nend];
  for (int p = g0 + tid; p < g1; p += 256) {
    const int2 r = part[p];
    const int d = ((unsigned)r.x) >> 15;
    const int s = ((r.x & 0x7FFF) << 2) | (r.y & 3);
    const int et = (r.y >> 2) & 7;
    const unsigned short n16 = (unsigned short)((r.y >> 5) & 0xFFFF);
    const float nf = (float)__builtin_bit_cast(_Float16, n16);
    const int pos = atomicAdd(&ncur[d - nb0], 1);
    em[pos] = make_int2((et << 20) | s, __float_as_int(nf));
  }
}

// ---------------- prep: fp16 conversions ----------------

__global__ __launch_bounds__(256) void k_prep_h(const float* __restrict__ h,
                                                _Float16* __restrict__ hh) {
  const int i = blockIdx.x * 256 + threadIdx.x;
  const float4 v = *(const float4*)&h[(size_t)i * 4];
  half4 o = {(_Float16)v.x, (_Float16)v.y, (_Float16)v.z, (_Float16)v.w};
  *(half4*)&hh[(size_t)i * 4] = o;
}

__global__ __launch_bounds__(256) void k_prep_b(const float* __restrict__ b0,
                                                const float* __restrict__ b1,
                                                const float* __restrict__ b2,
                                                _Float16* __restrict__ bbt) {
  const int g = blockIdx.x >> 6;
  const int idx = (blockIdx.x & 63) * 256 + threadIdx.x;
  const float* bases = (g == 0) ? b0 : (g == 1) ? b1 : b2;
  const int o = idx >> 8, k = idx & 255;
  const int b = k >> 6, i = k & 63;
  bbt[g * 16384 + idx] = (_Float16)bases[b * 4096 + i * 64 + o];
}

// ---------------- fused layer: gather + basis-GEMM (MFMA) ----------------
// Block = 16 dst nodes. Edges staged zero-padded per node (16 x NDCAP slots):
// inner loop is branchless (pad slots: wn=0, src=0 -> harmless broadcast).
// Rare overflow (deg > NDCAP) -> whole-block slow path from global em.
__global__ __launch_bounds__(256, 6) void k_layer(const _Float16* __restrict__ hh,
                                                  const int* __restrict__ off,
                                                  const int2* __restrict__ em,
                                                  const float* __restrict__ wcomp,
                                                  const _Float16* __restrict__ bbt,
                                                  _Float16* __restrict__ out16,
                                                  float* __restrict__ out32) {
  __shared__ _Float16 Ash[16 * 264];
  __shared__ int2 ems[16 * NDCAP];
  __shared__ float4 wcs[8];
  __shared__ int offs[17];
  __shared__ int ovf;
  const int tid = threadIdx.x;
  const int lane = tid & 63;
  const int wv = tid >> 6;
  const int n0 = blockIdx.x * 16;

  if (tid < 17) offs[tid] = off[n0 + tid];
  if (tid == 0) ovf = 0;
  if (tid < 8) wcs[tid] = ((const float4*)wcomp)[tid];
  for (int i = tid; i < 16 * NDCAP; i += 256) ems[i] = make_int2(0, 0);
  __syncthreads();

  const int e0 = offs[0];
  const int len = offs[16] - e0;
  for (int i = tid; i < len; i += 256) {
    const int2 r = em[e0 + i];
    const int g = e0 + i;
    int lo = 0, hi = 15;
    while (lo < hi) { const int mid = (lo + hi + 1) >> 1; if (offs[mid] <= g) lo = mid; else hi = mid - 1; }
    const int rank = g - offs[lo];
    if (rank < NDCAP) ems[lo * NDCAP + rank] = r;
    else ovf = 1;
  }
  __syncthreads();

  const _Float16* hl = hh + lane;
  if (!ovf) {
    // fast path: branchless batches of 8 from zero-padded per-node LDS
    for (int q = 0; q < 4; ++q) {
      const int m = wv * 4 + q;
      const int cnt = offs[m + 1] - offs[m];
      const int nbat = (cnt + 7) >> 3;
      const int2* ep = &ems[m * NDCAP];
      float a0 = 0.f, a1 = 0.f, a2 = 0.f, a3 = 0.f;
      for (int b = 0; b < nbat; ++b) {
        int2 mm[8];
#pragma unroll
        for (int j = 0; j < 8; ++j) mm[j] = ep[b * 8 + j];
        float hv[8];
#pragma unroll
        for (int j = 0; j < 8; ++j)
          hv[j] = (float)hl[(size_t)(mm[j].x & 0xFFFFF) << 6];
#pragma unroll
        for (int j = 0; j < 8; ++j) {
          const float4 w = wcs[mm[j].x >> 20];
          const float t = __int_as_float(mm[j].y) * hv[j];
          a0 = fmaf(t, w.x, a0); a1 = fmaf(t, w.y, a1);
          a2 = fmaf(t, w.z, a2); a3 = fmaf(t, w.w, a3);
        }
      }
      _Float16* ar = &Ash[m * 264];
      ar[lane]       = (_Float16)a0;
      ar[64 + lane]  = (_Float16)a1;
      ar[128 + lane] = (_Float16)a2;
      ar[192 + lane] = (_Float16)a3;
    }
  } else {
    // slow path: clamped batches straight from global em
    for (int q = 0; q < 4; ++q) {
      const int m = wv * 4 + q;
      const int p0 = offs[m], p1 = offs[m + 1];
      float a0 = 0.f, a1 = 0.f, a2 = 0.f, a3 = 0.f;
      for (int p = p0; p < p1; p += 8) {
#pragma unroll
        for (int j = 0; j < 8; ++j) {
          const bool live = (p + j < p1);
          const int idx = live ? p + j : p1 - 1;
          const int2 mm = em[idx];
          const float hv = (float)hl[(size_t)(mm.x & 0xFFFFF) << 6];
          const float wn = live ? __int_as_float(mm.y) : 0.f;
          const float4 w = wcs[mm.x >> 20];
          const float t = wn * hv;
          a0 = fmaf(t, w.x, a0); a1 = fmaf(t, w.y, a1);
          a2 = fmaf(t, w.z, a2); a3 = fmaf(t, w.w, a3);
        }
      }
      _Float16* ar = &Ash[m * 264];
      ar[lane]       = (_Float16)a0;
      ar[64 + lane]  = (_Float16)a1;
      ar[128 + lane] = (_Float16)a2;
      ar[192 + lane] = (_Float16)a3;
    }
  }
  __syncthreads();

  // MFMA: C[16 nodes][16 outs] per wave, outs = wv*16..+15, K = 256.
  const int col = lane & 15;
  const int quad = lane >> 4;
  const int obase = wv * 16 + col;
  const _Float16* ap = &Ash[col * 264 + quad * 8];
  const _Float16* bp = &bbt[(size_t)obase * 256 + quad * 8];
  floatx4 acc = {0.f, 0.f, 0.f, 0.f};
#pragma unroll
  for (int s = 0; s < 8; ++s) {
    const half8 af = *(const half8*)(ap + s * 32);
    const half8 bf = *(const half8*)(bp + s * 32);
    acc = __builtin_amdgcn_mfma_f32_16x16x32_f16(af, bf, acc, 0, 0, 0);
  }
  if (out16) {
#pragma unroll
    for (int r = 0; r < 4; ++r) {
      const float c = fmaxf(acc[r], 0.f);
      out16[(size_t)(n0 + quad * 4 + r) * 64 + obase] = (_Float16)c;
    }
  } else {
#pragma unroll
    for (int r = 0; r < 4; ++r) {
      out32[(size_t)(n0 + quad * 4 + r) * 64 + obase] = acc[r];
    }
  }
}

// decoder: rec[n] = b2 + sum_o relu(b1[o] + henc[n,:]@w1[:,o]) * w2[o]
__global__ __launch_bounds__(256) void k_dec(const float* __restrict__ henc,
                                             const float* __restrict__ w1,
                                             const float* __restrict__ b1,
                                             const float* __restrict__ w2,
                                             const float* __restrict__ b2,
                                             float* __restrict__ rec) {
  __shared__ float w1s[64 * 64];
  __shared__ float hs[16 * 68];
  const int tid = threadIdx.x;
  for (int r = tid; r < 1024; r += 256)
    *(float4*)&w1s[r * 4] = *(const float4*)&w1[r * 4];
  const int og = tid & 15;
  const int nl = tid >> 4;
  const float4 wv2 = *(const float4*)&w2[og * 4];
  const float4 bv1 = *(const float4*)&b1[og * 4];
  const float b2v = b2[0];
  for (int t0 = blockIdx.x * 16; t0 < NN; t0 += gridDim.x * 16) {
    __syncthreads();
    {
      const float4 hv = *(const float4*)&henc[(size_t)t0 * 64 + tid * 4];
      *(float4*)&hs[(tid >> 4) * 68 + (tid & 15) * 4] = hv;
    }
    __syncthreads();
    float4 acc = bv1;
    const float* hr = &hs[nl * 68];
#pragma unroll 8
    for (int i = 0; i < 64; ++i) {
      const float hv = hr[i];
      const float4 wv = *(const float4*)&w1s[i * 64 + og * 4];
      acc.x = fmaf(hv, wv.x, acc.x); acc.y = fmaf(hv, wv.y, acc.y);
      acc.z = fmaf(hv, wv.z, acc.z); acc.w = fmaf(hv, wv.w, acc.w);
    }
    acc.x = fmaxf(acc.x, 0.f); acc.y = fmaxf(acc.y, 0.f);
    acc.z = fmaxf(acc.z, 0.f); acc.w = fmaxf(acc.w, 0.f);
    float v = acc.x * wv2.x + acc.y * wv2.y + acc.z * wv2.z + acc.w * wv2.w;
    v += __shfl_xor(v, 1); v += __shfl_xor(v, 2);
    v += __shfl_xor(v, 4); v += __shfl_xor(v, 8);
    if (og == 0) rec[t0 + nl] = v + b2v;
  }
}

// ---------------- launch ----------------

extern "C" void kernel_launch(void* const* d_in, const int* in_sizes, int n_in,
                              void* d_out, int out_size, void* d_ws, size_t ws_size,
                              hipStream_t stream) {
  const float* h     = (const float*)d_in[0];
  const int*   src   = (const int*)d_in[1];
  const int*   dst   = (const int*)d_in[2];
  const int*   etype = (const int*)d_in[3];
  const float* norm  = (const float*)d_in[4];
  const float* bases[3] = {(const float*)d_in[5], (const float*)d_in[7], (const float*)d_in[9]};
  const float* wcomp[3] = {(const float*)d_in[6], (const float*)d_in[8], (const float*)d_in[10]};
  const float* dw1 = (const float*)d_in[11];
  const float* db1 = (const float*)d_in[12];
  const float* dw2 = (const float*)d_in[13];
  const float* db2 = (const float*)d_in[14];

  float* rec  = (float*)d_out;        // [N]
  float* henc = (float*)d_out + NN;   // [N,64] fp32 (layer-3 output)

  // workspace carve-up (16B-aligned)
  char* ws = (char*)d_ws;
  int*      off    = (int*)(ws + 0);              // (N+1) ints
  int*      cnt    = (int*)(ws + 400512);         // N ints (histogram)
  int*      bsum   = (int*)(ws + 800512);         // NB ints
  int*      gcur   = (int*)(ws + 801024);         // NBK ints (bucket cursors)
  int2*     em     = (int2*)(ws + 802048);        // E records, dst-sorted
  _Float16* hh     = (_Float16*)(ws + 13602048);  // [N][64] fp16
  _Float16* h1f    = (_Float16*)(ws + 26402048);  // [N][64] fp16 (aliased by part)
  _Float16* h2f    = (_Float16*)(ws + 39202048);  // [N][64] fp16
  _Float16* bbt    = (_Float16*)(ws + 52002048);  // [3][64][256] fp16
  int2*     part   = (int2*)h1f;                  // E records, bucket-partitioned
                                                  // (consumed before h1f written)

  // ---- build dst-sorted CSR (two-phase coalesced partition) ----
  hipMemsetAsync(cnt, 0, NN * sizeof(int), stream);
  k_hist<<<(EE / 4 + 255) / 256, 256, 0, stream>>>((const int4*)dst, cnt);
  k_scan1<<<NB, 256, 0, stream>>>(cnt, off, bsum);
  k_scan2<<<1, 128, 0, stream>>>(bsum);
  k_scan3<<<(NN + 255) / 256, 256, 0, stream>>>(off, bsum);
  k_initg<<<1, 256, 0, stream>>>(off, gcur);
  k_part<<<256, 256, 0, stream>>>(dst, src, etype, norm, gcur, part);
  k_part2<<<NBK, 256, 0, stream>>>(off, part, em);

  // ---- fp16 prep ----
  k_prep_h<<<6250, 256, 0, stream>>>(h, hh);
  k_prep_b<<<192, 256, 0, stream>>>(bases[0], bases[1], bases[2], bbt);

  // ---- fused layers ----
  k_layer<<<NN / 16, 256, 0, stream>>>(hh,  off, em, wcomp[0], bbt,         h1f, nullptr);
  k_layer<<<NN / 16, 256, 0, stream>>>(h1f, off, em, wcomp[1], bbt + 16384, h2f, nullptr);
  k_layer<<<NN / 16, 256, 0, stream>>>(h2f, off, em, wcomp[2], bbt + 32768, nullptr, henc);

  // ---- decoder ----
  k_dec<<<256, 256, 0, stream>>>(henc, dw1, db1, dw2, db2, rec);
}

// Round 6
// 440.960 us; speedup vs baseline: 2.5336x; 1.0658x over previous
//
#include <hip/hip_runtime.h>

typedef _Float16 half8 __attribute__((ext_vector_type(8)));
typedef _Float16 half4 __attribute__((ext_vector_type(4)));
typedef _Float16 half2v __attribute__((ext_vector_type(2)));
typedef float floatx4 __attribute__((ext_vector_type(4)));

// Problem constants (fixed by reference)
constexpr int NN = 100000;   // nodes
constexpr int EE = 1600000;  // edges
constexpr int NB = 98;       // scan blocks: ceil(100000/1024)
constexpr int NBK = 196;     // partition buckets: ceil(100000/512)
constexpr int CHUNK = 6250;  // edges per k_part block (EE/256)
constexpr int NDCAP = 40;    // per-node LDS edge cap (mean deg 16; mult of 8)

// ---------------- CSR build ----------------

__global__ __launch_bounds__(256) void k_hist(const int4* __restrict__ dst4,
                                              int* __restrict__ cnt) {
  int i = blockIdx.x * 256 + threadIdx.x;
  if (i < EE / 4) {
    const int4 d = dst4[i];
    atomicAdd(&cnt[d.x], 1);
    atomicAdd(&cnt[d.y], 1);
    atomicAdd(&cnt[d.z], 1);
    atomicAdd(&cnt[d.w], 1);
  }
}

__global__ __launch_bounds__(256) void k_scan1(const int* __restrict__ cnt,
                                               int* __restrict__ off,
                                               int* __restrict__ bsum) {
  __shared__ int sh[256];
  const int tid = threadIdx.x;
  const int base = blockIdx.x * 1024 + tid * 4;
  int c0 = (base + 0 < NN) ? cnt[base + 0] : 0;
  int c1 = (base + 1 < NN) ? cnt[base + 1] : 0;
  int c2 = (base + 2 < NN) ? cnt[base + 2] : 0;
  int c3 = (base + 3 < NN) ? cnt[base + 3] : 0;
  const int tsum = c0 + c1 + c2 + c3;
  sh[tid] = tsum;
  __syncthreads();
  int run = tsum;
  for (int d = 1; d < 256; d <<= 1) {
    int v = (tid >= d) ? sh[tid - d] : 0;
    __syncthreads();
    run += v;
    sh[tid] = run;
    __syncthreads();
  }
  const int excl = run - tsum;
  if (base + 0 < NN) off[base + 0] = excl;
  if (base + 1 < NN) off[base + 1] = excl + c0;
  if (base + 2 < NN) off[base + 2] = excl + c0 + c1;
  if (base + 3 < NN) off[base + 3] = excl + c0 + c1 + c2;
  if (tid == 255) bsum[blockIdx.x] = run;
}

__global__ __launch_bounds__(128) void k_scan2(int* __restrict__ bsum) {
  __shared__ int tot0;
  const int tid = threadIdx.x;
  const int v = (tid < NB) ? bsum[tid] : 0;
  int incl = v;
  for (int d = 1; d < 64; d <<= 1) {
    const int t = __shfl_up(incl, d);
    if ((tid & 63) >= d) incl += t;
  }
  if (tid == 63) tot0 = incl;
  __syncthreads();
  if (tid >= 64) incl += tot0;
  if (tid < NB) bsum[tid] = incl - v;
}

// finalize off; also emit bucket cursors (gcur) for pass A
__global__ __launch_bounds__(256) void k_scan3(int* __restrict__ off,
                                               const int* __restrict__ bsum,
                                               int* __restrict__ gcur) {
  int i = blockIdx.x * 256 + threadIdx.x;
  if (i < NN) {
    const int v = off[i] + bsum[i >> 10];
    off[i] = v;
    if ((i & 511) == 0) gcur[i >> 9] = v;
  }
  if (i == 0) off[NN] = EE;
}

// ---- pass A: block-local counting sort into coarse buckets (dst>>9) ----
// record: x = (dst<<15) | (src>>2); y = (src&3) | (et<<2) | (norm_fp16<<5)
__global__ __launch_bounds__(256) void k_part(const int* __restrict__ dst,
                                              const int* __restrict__ src,
                                              const int* __restrict__ etype,
                                              const float* __restrict__ norm,
                                              int* __restrict__ gcur,
                                              int2* __restrict__ part) {
  __shared__ int2 ldata[CHUNK];             // 50000 B
  __shared__ unsigned char lbkt[CHUNK];     // 6250 B
  __shared__ int lhist[NBK], lbase[NBK + 1], lcur[NBK], gbase[NBK];
  __shared__ int sh[256];
  const int tid = threadIdx.x;
  const int e0 = blockIdx.x * CHUNK;

  for (int b = tid; b < NBK; b += 256) lhist[b] = 0;
  __syncthreads();
  for (int i = tid; i < CHUNK; i += 256)
    atomicAdd(&lhist[dst[e0 + i] >> 9], 1);
  __syncthreads();
  {
    const int v = (tid < NBK) ? lhist[tid] : 0;
    sh[tid] = v;
    __syncthreads();
    int run = v;
    for (int d = 1; d < 256; d <<= 1) {
      int t = (tid >= d) ? sh[tid - d] : 0;
      __syncthreads();
      run += t;
      sh[tid] = run;
      __syncthreads();
    }
    if (tid < NBK) {
      lbase[tid] = run - v;
      lcur[tid] = 0;
      gbase[tid] = atomicAdd(&gcur[tid], v);
    }
    if (tid == 0) lbase[NBK] = CHUNK;
  }
  __syncthreads();
  for (int i = tid; i < CHUNK; i += 256) {
    const int e = e0 + i;
    const int d = dst[e], s = src[e], et = etype[e];
    const _Float16 nh = (_Float16)norm[e];
    const unsigned short n16 = __builtin_bit_cast(unsigned short, nh);
    const int bk = d >> 9;
    const int pos = lbase[bk] + atomicAdd(&lcur[bk], 1);
    ldata[pos] = make_int2((d << 15) | (s >> 2), (s & 3) | (et << 2) | ((int)n16 << 5));
    lbkt[pos] = (unsigned char)(bk & 0xFF);
  }
  __syncthreads();
  for (int i = tid; i < CHUNK; i += 256) {
    int bk = (int)lbkt[i];
    part[gbase[bk] + (i - lbase[bk])] = ldata[i];
  }
}

// ---- pass B: exact placement within each bucket via LDS node cursors ----
__global__ __launch_bounds__(256) void k_part2(const int* __restrict__ off,
                                               const int2* __restrict__ part,
                                               int2* __restrict__ em) {
  __shared__ int ncur[512];
  const int tid = threadIdx.x;
  const int nb0 = blockIdx.x << 9;
  for (int i = tid; i < 512; i += 256) {
    const int n = nb0 + i;
    ncur[i] = (n < NN) ? off[n] : EE;
  }
  __syncthreads();
  const int g0 = off[nb0];
  const int nend = (nb0 + 512 < NN) ? nb0 + 512 : NN;
  const int g1 = off[nend];
  for (int p = g0 + tid; p < g1; p += 256) {
    const int2 r = part[p];
    const int d = ((unsigned)r.x) >> 15;
    const int s = ((r.x & 0x7FFF) << 2) | (r.y & 3);
    const int et = (r.y >> 2) & 7;
    const unsigned short n16 = (unsigned short)((r.y >> 5) & 0xFFFF);
    const float nf = (float)__builtin_bit_cast(_Float16, n16);
    const int pos = atomicAdd(&ncur[d - nb0], 1);
    em[pos] = make_int2((et << 20) | s, __float_as_int(nf));
  }
}

// ---------------- prep: fp16 conversions (h + all 3 bases, one launch) ----------------

__global__ __launch_bounds__(256) void k_prep(const float* __restrict__ h,
                                              _Float16* __restrict__ hh,
                                              const float* __restrict__ b0,
                                              const float* __restrict__ b1,
                                              const float* __restrict__ b2,
                                              _Float16* __restrict__ bbt) {
  const int bx = blockIdx.x;
  if (bx < 6250) {
    const int i = bx * 256 + threadIdx.x;
    const float4 v = *(const float4*)&h[(size_t)i * 4];
    half4 o = {(_Float16)v.x, (_Float16)v.y, (_Float16)v.z, (_Float16)v.w};
    *(half4*)&hh[(size_t)i * 4] = o;
  } else {
    const int g = (bx - 6250) >> 6;
    const int idx = ((bx - 6250) & 63) * 256 + threadIdx.x;
    const float* bases = (g == 0) ? b0 : (g == 1) ? b1 : b2;
    const int o = idx >> 8, k = idx & 255;
    const int b = k >> 6, i = k & 63;
    bbt[g * 16384 + idx] = (_Float16)bases[b * 4096 + i * 64 + o];
  }
}

// ---------------- fused layer: gather + basis-GEMM (MFMA) ----------------
// Block = 16 dst nodes. Staging precomputes per-edge c_b = norm*wcomp[et][b]
// (fp16) into 16 B LDS records {src, c01, c23, 0}, zero-padded per node.
// Main loop: 2 edges per wave (32-lane groups, half2 gathers); per edge-pair:
// 1 ds_read_b128 + 1 mad + 1 global_load_dword + 8 fma_mix. Cross-group
// combine via shfl_xor(32). Then 16x16 MFMA chain (K=256) per wave.
__global__ __launch_bounds__(256, 8) void k_layer(const _Float16* __restrict__ hh,
                                                  const int* __restrict__ off,
                                                  const int2* __restrict__ em,
                                                  const float* __restrict__ wcomp,
                                                  const _Float16* __restrict__ bbt,
                                                  _Float16* __restrict__ out16,
                                                  float* __restrict__ out32) {
  __shared__ _Float16 Ash[16 * 264];   // 8448 B
  __shared__ int4 ems[16 * NDCAP];     // 10240 B
  __shared__ float4 wcs[8];
  __shared__ int offs[17];
  __shared__ int ovf;
  const int tid = threadIdx.x;
  const int lane = tid & 63;
  const int wv = tid >> 6;
  const int n0 = blockIdx.x * 16;

  if (tid < 17) offs[tid] = off[n0 + tid];
  if (tid == 0) ovf = 0;
  if (tid < 8) wcs[tid] = ((const float4*)wcomp)[tid];
  for (int i = tid; i < 16 * NDCAP; i += 256) ems[i] = make_int4(0, 0, 0, 0);
  __syncthreads();

  const int e0 = offs[0];
  const int len = offs[16] - e0;
  for (int i = tid; i < len; i += 256) {
    const int g = e0 + i;
    const int2 r = em[g];
    int lo = 0, hi = 15;
    while (lo < hi) { const int mid = (lo + hi + 1) >> 1; if (offs[mid] <= g) lo = mid; else hi = mid - 1; }
    const int rank = g - offs[lo];
    const int et = r.x >> 20;
    const int s = r.x & 0xFFFFF;
    const float nf = __int_as_float(r.y);
    const float4 w = wcs[et];
    half2v c01 = {(_Float16)(nf * w.x), (_Float16)(nf * w.y)};
    half2v c23 = {(_Float16)(nf * w.z), (_Float16)(nf * w.w)};
    if (rank < NDCAP)
      ems[lo * NDCAP + rank] = make_int4(s, __builtin_bit_cast(int, c01),
                                         __builtin_bit_cast(int, c23), 0);
    else ovf = 1;
  }
  __syncthreads();

  if (!ovf) {
    // fast path: 2 edges/wave (lane groups of 32), half2 feature pairs
    const int fl = lane & 31;
    const int eg = lane >> 5;
    const half2v* __restrict__ hp = (const half2v*)hh;
    for (int q = 0; q < 4; ++q) {
      const int m = wv * 4 + q;
      const int cnt = offs[m + 1] - offs[m];
      const int nbat = (cnt + 7) >> 3;
      const int4* ep = &ems[m * NDCAP + eg * 4];
      float a0 = 0.f, a1 = 0.f, a2 = 0.f, a3 = 0.f;
      float a4 = 0.f, a5 = 0.f, a6 = 0.f, a7 = 0.f;
      for (int b = 0; b < nbat; ++b) {
        int4 rr[4];
#pragma unroll
        for (int j = 0; j < 4; ++j) rr[j] = ep[b * 8 + j];
        half2v hv[4];
#pragma unroll
        for (int j = 0; j < 4; ++j)
          hv[j] = hp[(unsigned)rr[j].x * 32u + fl];
#pragma unroll
        for (int j = 0; j < 4; ++j) {
          const half2v c01 = __builtin_bit_cast(half2v, rr[j].y);
          const half2v c23 = __builtin_bit_cast(half2v, rr[j].z);
          const float h0 = (float)hv[j][0], h1 = (float)hv[j][1];
          a0 = fmaf(h0, (float)c01[0], a0); a1 = fmaf(h1, (float)c01[0], a1);
          a2 = fmaf(h0, (float)c01[1], a2); a3 = fmaf(h1, (float)c01[1], a3);
          a4 = fmaf(h0, (float)c23[0], a4); a5 = fmaf(h1, (float)c23[0], a5);
          a6 = fmaf(h0, (float)c23[1], a6); a7 = fmaf(h1, (float)c23[1], a7);
        }
      }
      a0 += __shfl_xor(a0, 32); a1 += __shfl_xor(a1, 32);
      a2 += __shfl_xor(a2, 32); a3 += __shfl_xor(a3, 32);
      a4 += __shfl_xor(a4, 32); a5 += __shfl_xor(a5, 32);
      a6 += __shfl_xor(a6, 32); a7 += __shfl_xor(a7, 32);
      if (eg == 0) {
        _Float16* ar = &Ash[m * 264];
        *(half2v*)&ar[0 * 64 + 2 * fl] = half2v{(_Float16)a0, (_Float16)a1};
        *(half2v*)&ar[1 * 64 + 2 * fl] = half2v{(_Float16)a2, (_Float16)a3};
        *(half2v*)&ar[2 * 64 + 2 * fl] = half2v{(_Float16)a4, (_Float16)a5};
        *(half2v*)&ar[3 * 64 + 2 * fl] = half2v{(_Float16)a6, (_Float16)a7};
      }
    }
  } else {
    // slow path (deg > NDCAP): clamped batches straight from global em
    const _Float16* hl = hh + lane;
    for (int q = 0; q < 4; ++q) {
      const int m = wv * 4 + q;
      const int p0 = offs[m], p1 = offs[m + 1];
      float a0 = 0.f, a1 = 0.f, a2 = 0.f, a3 = 0.f;
      for (int p = p0; p < p1; p += 8) {
#pragma unroll
        for (int j = 0; j < 8; ++j) {
          const bool live = (p + j < p1);
          const int idx = live ? p + j : p1 - 1;
          const int2 mm = em[idx];
          const float hv = (float)hl[(size_t)(mm.x & 0xFFFFF) << 6];
          const float wn = live ? __int_as_float(mm.y) : 0.f;
          const float4 w = wcs[mm.x >> 20];
          const float t = wn * hv;
          a0 = fmaf(t, w.x, a0); a1 = fmaf(t, w.y, a1);
          a2 = fmaf(t, w.z, a2); a3 = fmaf(t, w.w, a3);
        }
      }
      _Float16* ar = &Ash[m * 264];
      ar[lane]       = (_Float16)a0;
      ar[64 + lane]  = (_Float16)a1;
      ar[128 + lane] = (_Float16)a2;
      ar[192 + lane] = (_Float16)a3;
    }
  }
  __syncthreads();

  // MFMA: C[16 nodes][16 outs] per wave, outs = wv*16..+15, K = 256.
  const int col = lane & 15;
  const int quad = lane >> 4;
  const int obase = wv * 16 + col;
  const _Float16* ap = &Ash[col * 264 + quad * 8];
  const _Float16* bp = &bbt[(size_t)obase * 256 + quad * 8];
  floatx4 acc = {0.f, 0.f, 0.f, 0.f};
#pragma unroll
  for (int s = 0; s < 8; ++s) {
    const half8 af = *(const half8*)(ap + s * 32);
    const half8 bf = *(const half8*)(bp + s * 32);
    acc = __builtin_amdgcn_mfma_f32_16x16x32_f16(af, bf, acc, 0, 0, 0);
  }
  if (out16) {
#pragma unroll
    for (int r = 0; r < 4; ++r) {
      const float c = fmaxf(acc[r], 0.f);
      out16[(size_t)(n0 + quad * 4 + r) * 64 + obase] = (_Float16)c;
    }
  } else {
#pragma unroll
    for (int r = 0; r < 4; ++r) {
      out32[(size_t)(n0 + quad * 4 + r) * 64 + obase] = acc[r];
    }
  }
}

// decoder: rec[n] = b2 + sum_o relu(b1[o] + henc[n,:]@w1[:,o]) * w2[o]
__global__ __launch_bounds__(256) void k_dec(const float* __restrict__ henc,
                                             const float* __restrict__ w1,
                                             const float* __restrict__ b1,
                                             const float* __restrict__ w2,
                                             const float* __restrict__ b2,
                                             float* __restrict__ rec) {
  __shared__ float w1s[64 * 64];
  __shared__ float hs[16 * 68];
  const int tid = threadIdx.x;
  for (int r = tid; r < 1024; r += 256)
    *(float4*)&w1s[r * 4] = *(const float4*)&w1[r * 4];
  const int og = tid & 15;
  const int nl = tid >> 4;
  const float4 wv2 = *(const float4*)&w2[og * 4];
  const float4 bv1 = *(const float4*)&b1[og * 4];
  const float b2v = b2[0];
  for (int t0 = blockIdx.x * 16; t0 < NN; t0 += gridDim.x * 16) {
    __syncthreads();
    {
      const float4 hv = *(const float4*)&henc[(size_t)t0 * 64 + tid * 4];
      *(float4*)&hs[(tid >> 4) * 68 + (tid & 15) * 4] = hv;
    }
    __syncthreads();
    float4 acc = bv1;
    const float* hr = &hs[nl * 68];
#pragma unroll 8
    for (int i = 0; i < 64; ++i) {
      const float hv = hr[i];
      const float4 wv = *(const float4*)&w1s[i * 64 + og * 4];
      acc.x = fmaf(hv, wv.x, acc.x); acc.y = fmaf(hv, wv.y, acc.y);
      acc.z = fmaf(hv, wv.z, acc.z); acc.w = fmaf(hv, wv.w, acc.w);
    }
    acc.x = fmaxf(acc.x, 0.f); acc.y = fmaxf(acc.y, 0.f);
    acc.z = fmaxf(acc.z, 0.f); acc.w = fmaxf(acc.w, 0.f);
    float v = acc.x * wv2.x + acc.y * wv2.y + acc.z * wv2.z + acc.w * wv2.w;
    v += __shfl_xor(v, 1); v += __shfl_xor(v, 2);
    v += __shfl_xor(v, 4); v += __shfl_xor(v, 8);
    if (og == 0) rec[t0 + nl] = v + b2v;
  }
}

// ---------------- launch ----------------

extern "C" void kernel_launch(void* const* d_in, const int* in_sizes, int n_in,
                              void* d_out, int out_size, void* d_ws, size_t ws_size,
                              hipStream_t stream) {
  const float* h     = (const float*)d_in[0];
  const int*   src   = (const int*)d_in[1];
  const int*   dst   = (const int*)d_in[2];
  const int*   etype = (const int*)d_in[3];
  const float* norm  = (const float*)d_in[4];
  const float* bases[3] = {(const float*)d_in[5], (const float*)d_in[7], (const float*)d_in[9]};
  const float* wcomp[3] = {(const float*)d_in[6], (const float*)d_in[8], (const float*)d_in[10]};
  const float* dw1 = (const float*)d_in[11];
  const float* db1 = (const float*)d_in[12];
  const float* dw2 = (const float*)d_in[13];
  const float* db2 = (const float*)d_in[14];

  float* rec  = (float*)d_out;        // [N]
  float* henc = (float*)d_out + NN;   // [N,64] fp32 (layer-3 output)

  // workspace carve-up (16B-aligned)
  char* ws = (char*)d_ws;
  int*      off    = (int*)(ws + 0);              // (N+1) ints
  int*      cnt    = (int*)(ws + 400512);         // N ints (histogram)
  int*      bsum   = (int*)(ws + 800512);         // NB ints
  int*      gcur   = (int*)(ws + 801024);         // NBK ints (bucket cursors)
  int2*     em     = (int2*)(ws + 802048);        // E records, dst-sorted
  _Float16* hh     = (_Float16*)(ws + 13602048);  // [N][64] fp16
  _Float16* h1f    = (_Float16*)(ws + 26402048);  // [N][64] fp16 (aliased by part)
  _Float16* h2f    = (_Float16*)(ws + 39202048);  // [N][64] fp16
  _Float16* bbt    = (_Float16*)(ws + 52002048);  // [3][64][256] fp16
  int2*     part   = (int2*)h1f;                  // E records, bucket-partitioned
                                                  // (consumed before h1f written)

  // ---- build dst-sorted CSR (two-phase coalesced partition) ----
  hipMemsetAsync(cnt, 0, NN * sizeof(int), stream);
  k_hist<<<(EE / 4 + 255) / 256, 256, 0, stream>>>((const int4*)dst, cnt);
  k_scan1<<<NB, 256, 0, stream>>>(cnt, off, bsum);
  k_scan2<<<1, 128, 0, stream>>>(bsum);
  k_scan3<<<(NN + 255) / 256, 256, 0, stream>>>(off, bsum, gcur);
  k_part<<<256, 256, 0, stream>>>(dst, src, etype, norm, gcur, part);
  k_part2<<<NBK, 256, 0, stream>>>(off, part, em);

  // ---- fp16 prep (h + bases) ----
  k_prep<<<6250 + 192, 256, 0, stream>>>(h, hh, bases[0], bases[1], bases[2], bbt);

  // ---- fused layers ----
  k_layer<<<NN / 16, 256, 0, stream>>>(hh,  off, em, wcomp[0], bbt,         h1f, nullptr);
  k_layer<<<NN / 16, 256, 0, stream>>>(h1f, off, em, wcomp[1], bbt + 16384, h2f, nullptr);
  k_layer<<<NN / 16, 256, 0, stream>>>(h2f, off, em, wcomp[2], bbt + 32768, nullptr, henc);

  // ---- decoder ----
  k_dec<<<256, 256, 0, stream>>>(henc, dw1, db1, dw2, db2, rec);
}

// Round 7
// 379.724 us; speedup vs baseline: 2.9422x; 1.1613x over previous
//
#include <hip/hip_runtime.h>

typedef _Float16 half8 __attribute__((ext_vector_type(8)));
typedef _Float16 half4 __attribute__((ext_vector_type(4)));
typedef _Float16 half2v __attribute__((ext_vector_type(2)));
typedef float floatx4 __attribute__((ext_vector_type(4)));

// Problem constants (fixed by reference)
constexpr int NN = 100000;   // nodes
constexpr int EE = 1600000;  // edges
constexpr int NBK = 196;     // partition buckets: ceil(100000/512)
constexpr int CHUNK = 6250;  // edges per k_part block (EE/256)
constexpr int CAPB = 12288;  // per-bucket slab capacity (mean 8192, sigma~90)
constexpr int NDCAP = 40;    // per-node LDS edge cap (mean deg 16; mult of 8)

// ---- pass A: block-local counting sort into coarse buckets (dst>>9) ----
// Buckets self-allocate into fixed slabs part[bk*CAPB ...]; gcur[bk] counts.
// record: x = (dst<<15) | (src>>2); y = (src&3) | (et<<2) | (norm_fp16<<5)
__global__ __launch_bounds__(256) void k_part(const int* __restrict__ dst,
                                              const int* __restrict__ src,
                                              const int* __restrict__ etype,
                                              const float* __restrict__ norm,
                                              int* __restrict__ gcur,
                                              int2* __restrict__ part) {
  __shared__ int2 ldata[CHUNK];             // 50000 B
  __shared__ unsigned char lbkt[CHUNK];     // 6250 B
  __shared__ int lhist[NBK], lbase[NBK + 1], lcur[NBK], gbase[NBK];
  __shared__ int sh[256];
  const int tid = threadIdx.x;
  const int e0 = blockIdx.x * CHUNK;

  for (int b = tid; b < NBK; b += 256) lhist[b] = 0;
  __syncthreads();
  for (int i = tid; i < CHUNK; i += 256)
    atomicAdd(&lhist[dst[e0 + i] >> 9], 1);
  __syncthreads();
  {
    const int v = (tid < NBK) ? lhist[tid] : 0;
    sh[tid] = v;
    __syncthreads();
    int run = v;
    for (int d = 1; d < 256; d <<= 1) {
      int t = (tid >= d) ? sh[tid - d] : 0;
      __syncthreads();
      run += t;
      sh[tid] = run;
      __syncthreads();
    }
    if (tid < NBK) {
      lbase[tid] = run - v;
      lcur[tid] = 0;
      gbase[tid] = tid * CAPB + atomicAdd(&gcur[tid], v);
    }
    if (tid == 0) lbase[NBK] = CHUNK;
  }
  __syncthreads();
  for (int i = tid; i < CHUNK; i += 256) {
    const int e = e0 + i;
    const int d = dst[e], s = src[e], et = etype[e];
    const _Float16 nh = (_Float16)norm[e];
    const unsigned short n16 = __builtin_bit_cast(unsigned short, nh);
    const int bk = d >> 9;
    const int pos = lbase[bk] + atomicAdd(&lcur[bk], 1);
    ldata[pos] = make_int2((d << 15) | (s >> 2), (s & 3) | (et << 2) | ((int)n16 << 5));
    lbkt[pos] = (unsigned char)bk;
  }
  __syncthreads();
  for (int i = tid; i < CHUNK; i += 256) {
    const int bk = (int)lbkt[i];
    part[gbase[bk] + (i - lbase[bk])] = ldata[i];
  }
}

// ---- scan of 196 bucket counts -> global edge bases (1 block) ----
__global__ __launch_bounds__(256) void k_scanB(const int* __restrict__ gcur,
                                               int* __restrict__ ebase) {
  __shared__ int wsum[4];
  const int tid = threadIdx.x;
  const int v = (tid < NBK) ? gcur[tid] : 0;
  int incl = v;
  for (int d = 1; d < 64; d <<= 1) {
    const int t = __shfl_up(incl, d);
    if ((tid & 63) >= d) incl += t;
  }
  if ((tid & 63) == 63) wsum[tid >> 6] = incl;
  __syncthreads();
  int add = 0;
  for (int w = 0; w < (tid >> 6); ++w) add += wsum[w];
  incl += add;
  if (tid < NBK) ebase[tid] = incl - v;
  if (tid == NBK - 1) ebase[NBK] = incl;  // == EE
}

// ---- pass B: per-bucket node histogram + scan -> off[]; exact placement ----
__global__ __launch_bounds__(256) void k_part2(const int* __restrict__ gcur,
                                               const int* __restrict__ ebase,
                                               const int2* __restrict__ part,
                                               int* __restrict__ off,
                                               int2* __restrict__ em) {
  __shared__ int hcnt[512];
  __shared__ int obase[512];
  __shared__ int sh[256];
  const int tid = threadIdx.x;
  const int bk = blockIdx.x;
  const int nb0 = bk << 9;
  const int cntb = gcur[bk];
  const int base = ebase[bk];
  const int2* __restrict__ pp = part + (size_t)bk * CAPB;

  hcnt[tid] = 0;
  hcnt[tid + 256] = 0;
  __syncthreads();
  for (int i = tid; i < cntb; i += 256)
    atomicAdd(&hcnt[(((unsigned)pp[i].x) >> 15) & 511], 1);
  __syncthreads();
  // exclusive scan of 512 via 256 pair-sums
  const int c0 = hcnt[2 * tid], c1 = hcnt[2 * tid + 1];
  const int psum = c0 + c1;
  sh[tid] = psum;
  __syncthreads();
  int run = psum;
  for (int d = 1; d < 256; d <<= 1) {
    int t = (tid >= d) ? sh[tid - d] : 0;
    __syncthreads();
    run += t;
    sh[tid] = run;
    __syncthreads();
  }
  const int excl = run - psum;
  obase[2 * tid] = excl;
  obase[2 * tid + 1] = excl + c0;
  __syncthreads();
  // off[] (coalesced, two strides) + cursors
  {
    const int n = nb0 + tid;
    if (n < NN) off[n] = base + obase[tid];
    const int n2 = nb0 + 256 + tid;
    if (n2 < NN) off[n2] = base + obase[256 + tid];
  }
  if (bk == NBK - 1 && tid == 0) off[NN] = EE;
  hcnt[tid] = obase[tid];
  hcnt[tid + 256] = obase[tid + 256];
  __syncthreads();
  for (int i = tid; i < cntb; i += 256) {
    const int2 r = pp[i];
    const int d = ((unsigned)r.x) >> 15;
    const int s = ((r.x & 0x7FFF) << 2) | (r.y & 3);
    const int et = (r.y >> 2) & 7;
    const unsigned short n16 = (unsigned short)((r.y >> 5) & 0xFFFF);
    const float nf = (float)__builtin_bit_cast(_Float16, n16);
    const int pos = atomicAdd(&hcnt[d & 511], 1);
    em[base + pos] = make_int2((et << 20) | s, __float_as_int(nf));
  }
}

// ---------------- prep: fp16 conversions (h + all 3 bases, one launch) ----------------

__global__ __launch_bounds__(256) void k_prep(const float* __restrict__ h,
                                              _Float16* __restrict__ hh,
                                              const float* __restrict__ b0,
                                              const float* __restrict__ b1,
                                              const float* __restrict__ b2,
                                              _Float16* __restrict__ bbt) {
  const int bx = blockIdx.x;
  if (bx < 6250) {
    const int i = bx * 256 + threadIdx.x;
    const float4 v = *(const float4*)&h[(size_t)i * 4];
    half4 o = {(_Float16)v.x, (_Float16)v.y, (_Float16)v.z, (_Float16)v.w};
    *(half4*)&hh[(size_t)i * 4] = o;
  } else {
    const int g = (bx - 6250) >> 6;
    const int idx = ((bx - 6250) & 63) * 256 + threadIdx.x;
    const float* bases = (g == 0) ? b0 : (g == 1) ? b1 : b2;
    const int o = idx >> 8, k = idx & 255;
    const int b = k >> 6, i = k & 63;
    bbt[g * 16384 + idx] = (_Float16)bases[b * 4096 + i * 64 + o];
  }
}

// ---------------- fused layer: gather + basis-GEMM (MFMA) ----------------
// Block = 16 dst nodes. Staging precomputes per-edge c_b = norm*wcomp[et][b]
// (fp16) into 16 B LDS records {src, c01, c23, 0}, zero-padded per node.
// Main loop: 2 edges per wave (32-lane groups, half2 gathers). Cross-group
// combine via shfl_xor(32). Then 16x16 MFMA chain (K=256) per wave.
__global__ __launch_bounds__(256, 8) void k_layer(const _Float16* __restrict__ hh,
                                                  const int* __restrict__ off,
                                                  const int2* __restrict__ em,
                                                  const float* __restrict__ wcomp,
                                                  const _Float16* __restrict__ bbt,
                                                  _Float16* __restrict__ out16,
                                                  float* __restrict__ out32) {
  __shared__ _Float16 Ash[16 * 264];   // 8448 B
  __shared__ int4 ems[16 * NDCAP];     // 10240 B
  __shared__ float4 wcs[8];
  __shared__ int offs[17];
  __shared__ int ovf;
  const int tid = threadIdx.x;
  const int lane = tid & 63;
  const int wv = tid >> 6;
  const int n0 = blockIdx.x * 16;

  if (tid < 17) offs[tid] = off[n0 + tid];
  if (tid == 0) ovf = 0;
  if (tid < 8) wcs[tid] = ((const float4*)wcomp)[tid];
  for (int i = tid; i < 16 * NDCAP; i += 256) ems[i] = make_int4(0, 0, 0, 0);
  __syncthreads();

  const int e0 = offs[0];
  const int len = offs[16] - e0;
  for (int i = tid; i < len; i += 256) {
    const int g = e0 + i;
    const int2 r = em[g];
    int lo = 0, hi = 15;
    while (lo < hi) { const int mid = (lo + hi + 1) >> 1; if (offs[mid] <= g) lo = mid; else hi = mid - 1; }
    const int rank = g - offs[lo];
    const int et = r.x >> 20;
    const int s = r.x & 0xFFFFF;
    const float nf = __int_as_float(r.y);
    const float4 w = wcs[et];
    half2v c01 = {(_Float16)(nf * w.x), (_Float16)(nf * w.y)};
    half2v c23 = {(_Float16)(nf * w.z), (_Float16)(nf * w.w)};
    if (rank < NDCAP)
      ems[lo * NDCAP + rank] = make_int4(s, __builtin_bit_cast(int, c01),
                                         __builtin_bit_cast(int, c23), 0);
    else ovf = 1;
  }
  __syncthreads();

  if (!ovf) {
    const int fl = lane & 31;
    const int eg = lane >> 5;
    const half2v* __restrict__ hp = (const half2v*)hh;
    for (int q = 0; q < 4; ++q) {
      const int m = wv * 4 + q;
      const int cnt = offs[m + 1] - offs[m];
      const int nbat = (cnt + 7) >> 3;
      const int4* ep = &ems[m * NDCAP + eg * 4];
      float a0 = 0.f, a1 = 0.f, a2 = 0.f, a3 = 0.f;
      float a4 = 0.f, a5 = 0.f, a6 = 0.f, a7 = 0.f;
      for (int b = 0; b < nbat; ++b) {
        int4 rr[4];
#pragma unroll
        for (int j = 0; j < 4; ++j) rr[j] = ep[b * 8 + j];
        half2v hv[4];
#pragma unroll
        for (int j = 0; j < 4; ++j)
          hv[j] = hp[(unsigned)rr[j].x * 32u + fl];
#pragma unroll
        for (int j = 0; j < 4; ++j) {
          const half2v c01 = __builtin_bit_cast(half2v, rr[j].y);
          const half2v c23 = __builtin_bit_cast(half2v, rr[j].z);
          const float h0 = (float)hv[j][0], h1 = (float)hv[j][1];
          a0 = fmaf(h0, (float)c01[0], a0); a1 = fmaf(h1, (float)c01[0], a1);
          a2 = fmaf(h0, (float)c01[1], a2); a3 = fmaf(h1, (float)c01[1], a3);
          a4 = fmaf(h0, (float)c23[0], a4); a5 = fmaf(h1, (float)c23[0], a5);
          a6 = fmaf(h0, (float)c23[1], a6); a7 = fmaf(h1, (float)c23[1], a7);
        }
      }
      a0 += __shfl_xor(a0, 32); a1 += __shfl_xor(a1, 32);
      a2 += __shfl_xor(a2, 32); a3 += __shfl_xor(a3, 32);
      a4 += __shfl_xor(a4, 32); a5 += __shfl_xor(a5, 32);
      a6 += __shfl_xor(a6, 32); a7 += __shfl_xor(a7, 32);
      if (eg == 0) {
        _Float16* ar = &Ash[m * 264];
        *(half2v*)&ar[0 * 64 + 2 * fl] = half2v{(_Float16)a0, (_Float16)a1};
        *(half2v*)&ar[1 * 64 + 2 * fl] = half2v{(_Float16)a2, (_Float16)a3};
        *(half2v*)&ar[2 * 64 + 2 * fl] = half2v{(_Float16)a4, (_Float16)a5};
        *(half2v*)&ar[3 * 64 + 2 * fl] = half2v{(_Float16)a6, (_Float16)a7};
      }
    }
  } else {
    const _Float16* hl = hh + lane;
    for (int q = 0; q < 4; ++q) {
      const int m = wv * 4 + q;
      const int p0 = offs[m], p1 = offs[m + 1];
      float a0 = 0.f, a1 = 0.f, a2 = 0.f, a3 = 0.f;
      for (int p = p0; p < p1; p += 8) {
#pragma unroll
        for (int j = 0; j < 8; ++j) {
          const bool live = (p + j < p1);
          const int idx = live ? p + j : p1 - 1;
          const int2 mm = em[idx];
          const float hv = (float)hl[(size_t)(mm.x & 0xFFFFF) << 6];
          const float wn = live ? __int_as_float(mm.y) : 0.f;
          const float4 w = wcs[mm.x >> 20];
          const float t = wn * hv;
          a0 = fmaf(t, w.x, a0); a1 = fmaf(t, w.y, a1);
          a2 = fmaf(t, w.z, a2); a3 = fmaf(t, w.w, a3);
        }
      }
      _Float16* ar = &Ash[m * 264];
      ar[lane]       = (_Float16)a0;
      ar[64 + lane]  = (_Float16)a1;
      ar[128 + lane] = (_Float16)a2;
      ar[192 + lane] = (_Float16)a3;
    }
  }
  __syncthreads();

  // MFMA: C[16 nodes][16 outs] per wave, outs = wv*16..+15, K = 256.
  const int col = lane & 15;
  const int quad = lane >> 4;
  const int obase = wv * 16 + col;
  const _Float16* ap = &Ash[col * 264 + quad * 8];
  const _Float16* bp = &bbt[(size_t)obase * 256 + quad * 8];
  floatx4 acc = {0.f, 0.f, 0.f, 0.f};
#pragma unroll
  for (int s = 0; s < 8; ++s) {
    const half8 af = *(const half8*)(ap + s * 32);
    const half8 bf = *(const half8*)(bp + s * 32);
    acc = __builtin_amdgcn_mfma_f32_16x16x32_f16(af, bf, acc, 0, 0, 0);
  }
  if (out16) {
#pragma unroll
    for (int r = 0; r < 4; ++r) {
      const float c = fmaxf(acc[r], 0.f);
      out16[(size_t)(n0 + quad * 4 + r) * 64 + obase] = (_Float16)c;
    }
  } else {
#pragma unroll
    for (int r = 0; r < 4; ++r) {
      out32[(size_t)(n0 + quad * 4 + r) * 64 + obase] = acc[r];
    }
  }
}

// decoder: rec[n] = b2 + sum_o relu(b1[o] + henc[n,:]@w1[:,o]) * w2[o]
__global__ __launch_bounds__(256) void k_dec(const float* __restrict__ henc,
                                             const float* __restrict__ w1,
                                             const float* __restrict__ b1,
                                             const float* __restrict__ w2,
                                             const float* __restrict__ b2,
                                             float* __restrict__ rec) {
  __shared__ float w1s[64 * 64];
  __shared__ float hs[16 * 68];
  const int tid = threadIdx.x;
  for (int r = tid; r < 1024; r += 256)
    *(float4*)&w1s[r * 4] = *(const float4*)&w1[r * 4];
  const int og = tid & 15;
  const int nl = tid >> 4;
  const float4 wv2 = *(const float4*)&w2[og * 4];
  const float4 bv1 = *(const float4*)&b1[og * 4];
  const float b2v = b2[0];
  for (int t0 = blockIdx.x * 16; t0 < NN; t0 += gridDim.x * 16) {
    __syncthreads();
    {
      const float4 hv = *(const float4*)&henc[(size_t)t0 * 64 + tid * 4];
      *(float4*)&hs[(tid >> 4) * 68 + (tid & 15) * 4] = hv;
    }
    __syncthreads();
    float4 acc = bv1;
    const float* hr = &hs[nl * 68];
#pragma unroll 8
    for (int i = 0; i < 64; ++i) {
      const float hv = hr[i];
      const float4 wv = *(const float4*)&w1s[i * 64 + og * 4];
      acc.x = fmaf(hv, wv.x, acc.x); acc.y = fmaf(hv, wv.y, acc.y);
      acc.z = fmaf(hv, wv.z, acc.z); acc.w = fmaf(hv, wv.w, acc.w);
    }
    acc.x = fmaxf(acc.x, 0.f); acc.y = fmaxf(acc.y, 0.f);
    acc.z = fmaxf(acc.z, 0.f); acc.w = fmaxf(acc.w, 0.f);
    float v = acc.x * wv2.x + acc.y * wv2.y + acc.z * wv2.z + acc.w * wv2.w;
    v += __shfl_xor(v, 1); v += __shfl_xor(v, 2);
    v += __shfl_xor(v, 4); v += __shfl_xor(v, 8);
    if (og == 0) rec[t0 + nl] = v + b2v;
  }
}

// ---------------- launch ----------------

extern "C" void kernel_launch(void* const* d_in, const int* in_sizes, int n_in,
                              void* d_out, int out_size, void* d_ws, size_t ws_size,
                              hipStream_t stream) {
  const float* h     = (const float*)d_in[0];
  const int*   src   = (const int*)d_in[1];
  const int*   dst   = (const int*)d_in[2];
  const int*   etype = (const int*)d_in[3];
  const float* norm  = (const float*)d_in[4];
  const float* bases[3] = {(const float*)d_in[5], (const float*)d_in[7], (const float*)d_in[9]};
  const float* wcomp[3] = {(const float*)d_in[6], (const float*)d_in[8], (const float*)d_in[10]};
  const float* dw1 = (const float*)d_in[11];
  const float* db1 = (const float*)d_in[12];
  const float* dw2 = (const float*)d_in[13];
  const float* db2 = (const float*)d_in[14];

  float* rec  = (float*)d_out;        // [N]
  float* henc = (float*)d_out + NN;   // [N,64] fp32 (layer-3 output)

  // workspace carve-up (16B-aligned)
  char* ws = (char*)d_ws;
  int*      off    = (int*)(ws + 0);              // (N+1) ints
  int*      gcur   = (int*)(ws + 400512);         // NBK bucket counters
  int*      ebase  = (int*)(ws + 401536);         // NBK+1 bucket edge bases
  int2*     em     = (int2*)(ws + 402560);        // E records, dst-sorted
  _Float16* hh     = (_Float16*)(ws + 13202560);  // [N][64] fp16
  _Float16* h1f    = (_Float16*)(ws + 26002560);  // [N][64] fp16
  _Float16* h2f    = (_Float16*)(ws + 38802560);  // [N][64] fp16
  _Float16* bbt    = (_Float16*)(ws + 51602560);  // [3][64][256] fp16
  int2*     part   = (int2*)h1f;                  // NBK slabs x CAPB records
                                                  // (19.3 MB; consumed in
                                                  //  k_part2 before h1f/h2f
                                                  //  are written by layers)

  // ---- fp16 prep (h + bases) ----
  k_prep<<<6250 + 192, 256, 0, stream>>>(h, hh, bases[0], bases[1], bases[2], bbt);

  // ---- build dst-sorted CSR (self-allocating two-phase partition) ----
  hipMemsetAsync(gcur, 0, NBK * sizeof(int), stream);
  k_part<<<256, 256, 0, stream>>>(dst, src, etype, norm, gcur, part);
  k_scanB<<<1, 256, 0, stream>>>(gcur, ebase);
  k_part2<<<NBK, 256, 0, stream>>>(gcur, ebase, part, off, em);

  // ---- fused layers ----
  k_layer<<<NN / 16, 256, 0, stream>>>(hh,  off, em, wcomp[0], bbt,         h1f, nullptr);
  k_layer<<<NN / 16, 256, 0, stream>>>(h1f, off, em, wcomp[1], bbt + 16384, h2f, nullptr);
  k_layer<<<NN / 16, 256, 0, stream>>>(h2f, off, em, wcomp[2], bbt + 32768, nullptr, henc);

  // ---- decoder ----
  k_dec<<<256, 256, 0, stream>>>(henc, dw1, db1, dw2, db2, rec);
}

// Round 8
// 360.472 us; speedup vs baseline: 3.0994x; 1.0534x over previous
//
#include <hip/hip_runtime.h>

typedef _Float16 half8 __attribute__((ext_vector_type(8)));
typedef _Float16 half4 __attribute__((ext_vector_type(4)));
typedef _Float16 half2v __attribute__((ext_vector_type(2)));
typedef float floatx4 __attribute__((ext_vector_type(4)));

// Problem constants (fixed by reference)
constexpr int NN = 100000;   // nodes
constexpr int EE = 1600000;  // edges
constexpr int NBK = 196;     // partition buckets: ceil(100000/512)
constexpr int CHUNK = 3125;  // edges per k_part block (EE/512)
constexpr int CAPB = 12288;  // per-bucket slab capacity (mean 8192, sigma~90)
constexpr int NDCAP = 48;    // per-node LDS edge cap (mean deg 16; mult of 16)

// ---- pass A: block-local counting sort into coarse buckets (dst>>9) ----
// Buckets self-allocate into fixed slabs part[bk*CAPB ...]; gcur[bk] counts.
// record: x = (dst<<15) | (src>>2); y = (src&3) | (et<<2) | (norm_fp16<<5)
__global__ __launch_bounds__(256) void k_part(const int* __restrict__ dst,
                                              const int* __restrict__ src,
                                              const int* __restrict__ etype,
                                              const float* __restrict__ norm,
                                              int* __restrict__ gcur,
                                              int2* __restrict__ part) {
  __shared__ int2 ldata[CHUNK];             // 25000 B
  __shared__ unsigned char lbkt[CHUNK];     // 3125 B
  __shared__ int lhist[NBK], lbase[NBK + 1], lcur[NBK], gbase[NBK];
  __shared__ int sh[256];
  const int tid = threadIdx.x;
  const int e0 = blockIdx.x * CHUNK;

  for (int b = tid; b < NBK; b += 256) lhist[b] = 0;
  __syncthreads();
  for (int i = tid; i < CHUNK; i += 256)
    atomicAdd(&lhist[dst[e0 + i] >> 9], 1);
  __syncthreads();
  {
    const int v = (tid < NBK) ? lhist[tid] : 0;
    sh[tid] = v;
    __syncthreads();
    int run = v;
    for (int d = 1; d < 256; d <<= 1) {
      int t = (tid >= d) ? sh[tid - d] : 0;
      __syncthreads();
      run += t;
      sh[tid] = run;
      __syncthreads();
    }
    if (tid < NBK) {
      lbase[tid] = run - v;
      lcur[tid] = 0;
      gbase[tid] = tid * CAPB + atomicAdd(&gcur[tid], v);
    }
    if (tid == 0) lbase[NBK] = CHUNK;
  }
  __syncthreads();
  for (int i = tid; i < CHUNK; i += 256) {
    const int e = e0 + i;
    const int d = dst[e], s = src[e], et = etype[e];
    const _Float16 nh = (_Float16)norm[e];
    const unsigned short n16 = __builtin_bit_cast(unsigned short, nh);
    const int bk = d >> 9;
    const int pos = lbase[bk] + atomicAdd(&lcur[bk], 1);
    ldata[pos] = make_int2((d << 15) | (s >> 2), (s & 3) | (et << 2) | ((int)n16 << 5));
    lbkt[pos] = (unsigned char)bk;
  }
  __syncthreads();
  for (int i = tid; i < CHUNK; i += 256) {
    const int bk = (int)lbkt[i];
    part[gbase[bk] + (i - lbase[bk])] = ldata[i];
  }
}

// ---- pass B: per-bucket node histogram + scan -> off[]; exact placement ----
// 512 threads; bucket's global edge base computed in-block (sum of gcur[<bk]).
__global__ __launch_bounds__(512) void k_part2(const int* __restrict__ gcur,
                                               const int2* __restrict__ part,
                                               int* __restrict__ off,
                                               int2* __restrict__ em) {
  __shared__ int hcnt[512];
  __shared__ int wred[8];
  __shared__ int swsum[8];
  const int tid = threadIdx.x;
  const int bk = blockIdx.x;
  const int nb0 = bk << 9;
  const int2* __restrict__ pp = part + (size_t)bk * CAPB;

  // base = sum_{j<bk} gcur[j]  (block-wide reduction)
  {
    int pv = (tid < bk) ? gcur[tid] : 0;
    for (int d = 32; d > 0; d >>= 1) pv += __shfl_down(pv, d);
    if ((tid & 63) == 0) wred[tid >> 6] = pv;
  }
  hcnt[tid] = 0;
  __syncthreads();
  int base = 0;
#pragma unroll
  for (int w = 0; w < 8; ++w) base += wred[w];
  const int cntb = gcur[bk];

  for (int i = tid; i < cntb; i += 512)
    atomicAdd(&hcnt[(((unsigned)pp[i].x) >> 15) & 511], 1);
  __syncthreads();
  // exclusive scan of 512 counts (wave scans + wave-sum prefix)
  const int v = hcnt[tid];
  int incl = v;
  for (int d = 1; d < 64; d <<= 1) {
    const int t = __shfl_up(incl, d);
    if ((tid & 63) >= d) incl += t;
  }
  if ((tid & 63) == 63) swsum[tid >> 6] = incl;
  __syncthreads();
  int pre = 0;
  for (int w = 0; w < (tid >> 6); ++w) pre += swsum[w];
  const int excl = pre + incl - v;  // bucket-local exclusive offset
  {
    const int n = nb0 + tid;
    if (n < NN) off[n] = base + excl;
  }
  if (bk == NBK - 1 && tid == 0) off[NN] = EE;
  hcnt[tid] = excl;  // cursors (all reads of hcnt done pre-sync)
  __syncthreads();
  for (int i = tid; i < cntb; i += 512) {
    const int2 r = pp[i];
    const int d = ((unsigned)r.x) >> 15;
    const int s = ((r.x & 0x7FFF) << 2) | (r.y & 3);
    const int et = (r.y >> 2) & 7;
    const unsigned short n16 = (unsigned short)((r.y >> 5) & 0xFFFF);
    const float nf = (float)__builtin_bit_cast(_Float16, n16);
    const int pos = atomicAdd(&hcnt[d & 511], 1);
    em[base + pos] = make_int2((et << 20) | s, __float_as_int(nf));
  }
}

// ---------------- prep: fp16 conversions + gcur zeroing ----------------

__global__ __launch_bounds__(256) void k_prep(const float* __restrict__ h,
                                              _Float16* __restrict__ hh,
                                              const float* __restrict__ b0,
                                              const float* __restrict__ b1,
                                              const float* __restrict__ b2,
                                              _Float16* __restrict__ bbt,
                                              int* __restrict__ gcur) {
  const int bx = blockIdx.x;
  if (bx == 0 && threadIdx.x < NBK) gcur[threadIdx.x] = 0;
  if (bx < 6250) {
    const int i = bx * 256 + threadIdx.x;
    const float4 v = *(const float4*)&h[(size_t)i * 4];
    half4 o = {(_Float16)v.x, (_Float16)v.y, (_Float16)v.z, (_Float16)v.w};
    *(half4*)&hh[(size_t)i * 4] = o;
  } else {
    const int g = (bx - 6250) >> 6;
    const int idx = ((bx - 6250) & 63) * 256 + threadIdx.x;
    const float* bases = (g == 0) ? b0 : (g == 1) ? b1 : b2;
    const int o = idx >> 8, k = idx & 255;
    const int b = k >> 6, i = k & 63;
    bbt[g * 16384 + idx] = (_Float16)bases[b * 4096 + i * 64 + o];
  }
}

// ---------------- fused layer: gather + basis-GEMM (MFMA) ----------------
// Block = 16 dst nodes. Staging precomputes per-edge duplicated coefficient
// packs {c0c0,c1c1,c2c2,c3c3} (fp16) + src, zero-padded per node. Main loop:
// 2 edges per wave (32-lane groups), 16-slot batches (8 gathers in flight),
// 4 v_pk_fma_f16 per edge, no cvt. Cross-group combine via shfl_xor(32).
// Then 16x16 MFMA chain (K=256) per wave.
__global__ __launch_bounds__(256, 6) void k_layer(const _Float16* __restrict__ hh,
                                                  const int* __restrict__ off,
                                                  const int2* __restrict__ em,
                                                  const float* __restrict__ wcomp,
                                                  const _Float16* __restrict__ bbt,
                                                  _Float16* __restrict__ out16,
                                                  float* __restrict__ out32) {
  __shared__ _Float16 Ash[16 * 264];   // 8448 B
  __shared__ int  ems_s[16 * NDCAP];   // 3072 B: src per slot
  __shared__ int4 ems_c[16 * NDCAP];   // 12288 B: dup coeff packs per slot
  __shared__ float4 wcs[8];
  __shared__ int offs[17];
  __shared__ int ovf;
  const int tid = threadIdx.x;
  const int lane = tid & 63;
  const int wv = tid >> 6;
  const int n0 = blockIdx.x * 16;

  if (tid < 17) offs[tid] = off[n0 + tid];
  if (tid == 0) ovf = 0;
  if (tid < 8) wcs[tid] = ((const float4*)wcomp)[tid];
  for (int i = tid; i < 16 * NDCAP; i += 256) {
    ems_s[i] = 0;
    ems_c[i] = make_int4(0, 0, 0, 0);
  }
  __syncthreads();

  const int e0 = offs[0];
  const int len = offs[16] - e0;
  for (int i = tid; i < len; i += 256) {
    const int g = e0 + i;
    const int2 r = em[g];
    int lo = 0, hi = 15;
    while (lo < hi) { const int mid = (lo + hi + 1) >> 1; if (offs[mid] <= g) lo = mid; else hi = mid - 1; }
    const int rank = g - offs[lo];
    const int et = r.x >> 20;
    const int s = r.x & 0xFFFFF;
    const float nf = __int_as_float(r.y);
    const float4 w = wcs[et];
    const _Float16 c0 = (_Float16)(nf * w.x), c1 = (_Float16)(nf * w.y);
    const _Float16 c2 = (_Float16)(nf * w.z), c3 = (_Float16)(nf * w.w);
    const half2v p0 = {c0, c0}, p1 = {c1, c1}, p2 = {c2, c2}, p3 = {c3, c3};
    if (rank < NDCAP) {
      ems_s[lo * NDCAP + rank] = s;
      ems_c[lo * NDCAP + rank] = make_int4(
          __builtin_bit_cast(int, p0), __builtin_bit_cast(int, p1),
          __builtin_bit_cast(int, p2), __builtin_bit_cast(int, p3));
    } else ovf = 1;
  }
  __syncthreads();

  if (!ovf) {
    // fast path: fp16 packed accumulation, zero-padded 16-slot batches
    const int fl = lane & 31;   // feature pair index (feats 2fl, 2fl+1)
    const int eg = lane >> 5;   // edge group 0/1
    const half2v* __restrict__ hp = (const half2v*)hh;
    for (int q = 0; q < 4; ++q) {
      const int m = wv * 4 + q;
      const int cnt = offs[m + 1] - offs[m];
      const int nbat = (cnt + 15) >> 4;
      const int* sp = &ems_s[m * NDCAP + eg * 8];
      const int4* cp = &ems_c[m * NDCAP + eg * 8];
      half2v a0 = {0, 0}, a1 = {0, 0}, a2 = {0, 0}, a3 = {0, 0};
      for (int b = 0; b < nbat; ++b) {
        int s8[8];
#pragma unroll
        for (int j = 0; j < 8; ++j) s8[j] = sp[b * 16 + j];
        half2v hv[8];
#pragma unroll
        for (int j = 0; j < 8; ++j)
          hv[j] = hp[(unsigned)s8[j] * 32u + fl];
#pragma unroll
        for (int j = 0; j < 8; ++j) {
          const int4 cc = cp[b * 16 + j];
          a0 = a0 + hv[j] * __builtin_bit_cast(half2v, cc.x);
          a1 = a1 + hv[j] * __builtin_bit_cast(half2v, cc.y);
          a2 = a2 + hv[j] * __builtin_bit_cast(half2v, cc.z);
          a3 = a3 + hv[j] * __builtin_bit_cast(half2v, cc.w);
        }
      }
      a0 = a0 + __builtin_bit_cast(half2v, __shfl_xor(__builtin_bit_cast(int, a0), 32));
      a1 = a1 + __builtin_bit_cast(half2v, __shfl_xor(__builtin_bit_cast(int, a1), 32));
      a2 = a2 + __builtin_bit_cast(half2v, __shfl_xor(__builtin_bit_cast(int, a2), 32));
      a3 = a3 + __builtin_bit_cast(half2v, __shfl_xor(__builtin_bit_cast(int, a3), 32));
      if (eg == 0) {
        _Float16* ar = &Ash[m * 264];
        *(half2v*)&ar[0 * 64 + 2 * fl] = a0;
        *(half2v*)&ar[1 * 64 + 2 * fl] = a1;
        *(half2v*)&ar[2 * 64 + 2 * fl] = a2;
        *(half2v*)&ar[3 * 64 + 2 * fl] = a3;
      }
    }
  } else {
    // slow path (deg > NDCAP): fp32 clamped batches straight from global em
    const _Float16* hl = hh + lane;
    for (int q = 0; q < 4; ++q) {
      const int m = wv * 4 + q;
      const int p0 = offs[m], p1 = offs[m + 1];
      float a0 = 0.f, a1 = 0.f, a2 = 0.f, a3 = 0.f;
      for (int p = p0; p < p1; p += 8) {
#pragma unroll
        for (int j = 0; j < 8; ++j) {
          const bool live = (p + j < p1);
          const int idx = live ? p + j : p1 - 1;
          const int2 mm = em[idx];
          const float hv = (float)hl[(size_t)(mm.x & 0xFFFFF) << 6];
          const float wn = live ? __int_as_float(mm.y) : 0.f;
          const float4 w = wcs[mm.x >> 20];
          const float t = wn * hv;
          a0 = fmaf(t, w.x, a0); a1 = fmaf(t, w.y, a1);
          a2 = fmaf(t, w.z, a2); a3 = fmaf(t, w.w, a3);
        }
      }
      _Float16* ar = &Ash[m * 264];
      ar[lane]       = (_Float16)a0;
      ar[64 + lane]  = (_Float16)a1;
      ar[128 + lane] = (_Float16)a2;
      ar[192 + lane] = (_Float16)a3;
    }
  }
  __syncthreads();

  // MFMA: C[16 nodes][16 outs] per wave, outs = wv*16..+15, K = 256.
  const int col = lane & 15;
  const int quad = lane >> 4;
  const int obase = wv * 16 + col;
  const _Float16* ap = &Ash[col * 264 + quad * 8];
  const _Float16* bp = &bbt[(size_t)obase * 256 + quad * 8];
  floatx4 acc = {0.f, 0.f, 0.f, 0.f};
#pragma unroll
  for (int s = 0; s < 8; ++s) {
    const half8 af = *(const half8*)(ap + s * 32);
    const half8 bf = *(const half8*)(bp + s * 32);
    acc = __builtin_amdgcn_mfma_f32_16x16x32_f16(af, bf, acc, 0, 0, 0);
  }
  if (out16) {
#pragma unroll
    for (int r = 0; r < 4; ++r) {
      const float c = fmaxf(acc[r], 0.f);
      out16[(size_t)(n0 + quad * 4 + r) * 64 + obase] = (_Float16)c;
    }
  } else {
#pragma unroll
    for (int r = 0; r < 4; ++r) {
      out32[(size_t)(n0 + quad * 4 + r) * 64 + obase] = acc[r];
    }
  }
}

// decoder: rec[n] = b2 + sum_o relu(b1[o] + henc[n,:]@w1[:,o]) * w2[o]
__global__ __launch_bounds__(256) void k_dec(const float* __restrict__ henc,
                                             const float* __restrict__ w1,
                                             const float* __restrict__ b1,
                                             const float* __restrict__ w2,
                                             const float* __restrict__ b2,
                                             float* __restrict__ rec) {
  __shared__ float w1s[64 * 64];
  __shared__ float hs[16 * 68];
  const int tid = threadIdx.x;
  for (int r = tid; r < 1024; r += 256)
    *(float4*)&w1s[r * 4] = *(const float4*)&w1[r * 4];
  const int og = tid & 15;
  const int nl = tid >> 4;
  const float4 wv2 = *(const float4*)&w2[og * 4];
  const float4 bv1 = *(const float4*)&b1[og * 4];
  const float b2v = b2[0];
  for (int t0 = blockIdx.x * 16; t0 < NN; t0 += gridDim.x * 16) {
    __syncthreads();
    {
      const float4 hv = *(const float4*)&henc[(size_t)t0 * 64 + tid * 4];
      *(float4*)&hs[(tid >> 4) * 68 + (tid & 15) * 4] = hv;
    }
    __syncthreads();
    float4 acc = bv1;
    const float* hr = &hs[nl * 68];
#pragma unroll 8
    for (int i = 0; i < 64; ++i) {
      const float hv = hr[i];
      const float4 wv = *(const float4*)&w1s[i * 64 + og * 4];
      acc.x = fmaf(hv, wv.x, acc.x); acc.y = fmaf(hv, wv.y, acc.y);
      acc.z = fmaf(hv, wv.z, acc.z); acc.w = fmaf(hv, wv.w, acc.w);
    }
    acc.x = fmaxf(acc.x, 0.f); acc.y = fmaxf(acc.y, 0.f);
    acc.z = fmaxf(acc.z, 0.f); acc.w = fmaxf(acc.w, 0.f);
    float v = acc.x * wv2.x + acc.y * wv2.y + acc.z * wv2.z + acc.w * wv2.w;
    v += __shfl_xor(v, 1); v += __shfl_xor(v, 2);
    v += __shfl_xor(v, 4); v += __shfl_xor(v, 8);
    if (og == 0) rec[t0 + nl] = v + b2v;
  }
}

// ---------------- launch ----------------

extern "C" void kernel_launch(void* const* d_in, const int* in_sizes, int n_in,
                              void* d_out, int out_size, void* d_ws, size_t ws_size,
                              hipStream_t stream) {
  const float* h     = (const float*)d_in[0];
  const int*   src   = (const int*)d_in[1];
  const int*   dst   = (const int*)d_in[2];
  const int*   etype = (const int*)d_in[3];
  const float* norm  = (const float*)d_in[4];
  const float* bases[3] = {(const float*)d_in[5], (const float*)d_in[7], (const float*)d_in[9]};
  const float* wcomp[3] = {(const float*)d_in[6], (const float*)d_in[8], (const float*)d_in[10]};
  const float* dw1 = (const float*)d_in[11];
  const float* db1 = (const float*)d_in[12];
  const float* dw2 = (const float*)d_in[13];
  const float* db2 = (const float*)d_in[14];

  float* rec  = (float*)d_out;        // [N]
  float* henc = (float*)d_out + NN;   // [N,64] fp32 (layer-3 output)

  // workspace carve-up (16B-aligned)
  char* ws = (char*)d_ws;
  int*      off    = (int*)(ws + 0);              // (N+1) ints
  int*      gcur   = (int*)(ws + 400512);         // NBK bucket counters
  int2*     em     = (int2*)(ws + 402560);        // E records, dst-sorted
  _Float16* hh     = (_Float16*)(ws + 13202560);  // [N][64] fp16
  _Float16* h1f    = (_Float16*)(ws + 26002560);  // [N][64] fp16
  _Float16* h2f    = (_Float16*)(ws + 38802560);  // [N][64] fp16
  _Float16* bbt    = (_Float16*)(ws + 51602560);  // [3][64][256] fp16
  int2*     part   = (int2*)h1f;                  // NBK slabs x CAPB records
                                                  // (19.3 MB; consumed in
                                                  //  k_part2 before h1f/h2f
                                                  //  are written by layers)

  // ---- fp16 prep (h + bases) + gcur zeroing ----
  k_prep<<<6250 + 192, 256, 0, stream>>>(h, hh, bases[0], bases[1], bases[2], bbt, gcur);

  // ---- build dst-sorted CSR (self-allocating two-phase partition) ----
  k_part<<<512, 256, 0, stream>>>(dst, src, etype, norm, gcur, part);
  k_part2<<<NBK, 512, 0, stream>>>(gcur, part, off, em);

  // ---- fused layers ----
  k_layer<<<NN / 16, 256, 0, stream>>>(hh,  off, em, wcomp[0], bbt,         h1f, nullptr);
  k_layer<<<NN / 16, 256, 0, stream>>>(h1f, off, em, wcomp[1], bbt + 16384, h2f, nullptr);
  k_layer<<<NN / 16, 256, 0, stream>>>(h2f, off, em, wcomp[2], bbt + 32768, nullptr, henc);

  // ---- decoder ----
  k_dec<<<256, 256, 0, stream>>>(henc, dw1, db1, dw2, db2, rec);
}